// Round 2
// baseline (4188.959 us; speedup 1.0000x reference)
//
#include <hip/hip_runtime.h>
#include <hip/hip_bf16.h>

typedef unsigned int uint;
#define DI __device__ __forceinline__

// ---------------- sizes ----------------
constexpr int TC = 16;       // LSTM time chunk
// ws layout (float units). Aggressive aliasing:
//  region A (33,554,432 f-slots): y1/y2 as bf16 (67.1M elems) -> later s2 f32
//  region B (33,554,432 floats):  p1 -> p2 -> pre  (f32)
//  region D: small state
constexpr size_t OFF_A    = 0;
constexpr size_t OFF_B    = 33554432;
constexpr size_t OFF_D    = 67108864;
constexpr size_t OFF_WHHT = OFF_D;                 // bf16 [2][128*128*4] = 65536 f-slots
constexpr size_t OFF_H    = OFF_D + 65536;         // [2][2048][128]
constexpr size_t OFF_C    = OFF_H + 524288;
constexpr size_t OFF_HSUM = OFF_C + 524288;
constexpr size_t OFF_FEAT = OFF_HSUM + 524288;     // [2048][256]
constexpr size_t OFF_WH1  = OFF_FEAT + 524288;     // [2048][128]
constexpr size_t OFF_S1A  = OFF_WH1 + 262144;
constexpr size_t OFF_S2A  = OFF_S1A + 2048;
constexpr size_t OFF_H1   = OFF_S2A + 2048;
constexpr size_t OFF_WH2  = OFF_H1 + 262144;
constexpr size_t OFF_S1B  = OFF_WH2 + 262144;
constexpr size_t OFF_S2B  = OFF_S1B + 2048;
constexpr size_t OFF_STAT = OFF_S2B + 2048;        // sum[128] sumsq[128] scale[128] shift[128]
// total = 70,066,688 floats ~= 267 MB

DI float bf_lo(uint u){ union { uint i; float f; } v; v.i = u << 16;        return v.f; }
DI float bf_hi(uint u){ union { uint i; float f; } v; v.i = u & 0xffff0000u; return v.f; }
DI float sigmoidf_(float x){ return 1.0f/(1.0f + __expf(-x)); }
DI float tanhf_(float x){ float e = __expf(-2.0f*fabsf(x)); float r = (1.0f-e)/(1.0f+e); return x>=0.0f ? r : -r; }

// ---------------- conv1: x[2048][64][512] (f32) -> y bf16 ----------------
// block 256 = 64 co x 4 tgroups(16 t), t-tile 64. weights f32 LDS [192][65] (pad: both
// stage-write and read conflict-free). x staged bf16 (b128 carries 8 vals).
__global__ __launch_bounds__(256) void conv1_kernel(
    const float* __restrict__ x, const float* __restrict__ w,
    const float* __restrict__ bias, __hip_bfloat16* __restrict__ y)
{
  __shared__ __hip_bfloat16 xs[64][72];   // rows 144B (16B aligned)
  __shared__ float wsh[192*65];           // [ci*3+k][co]
  const int n = blockIdx.y, t0 = blockIdx.x*64, tid = threadIdx.x;
  for (int i = tid; i < 64*192; i += 256) {
    int co = i/192, r = i%192;
    wsh[r*65 + co] = w[i];
  }
  for (int i = tid; i < 64*66; i += 256) {
    int ci = i/66, j = i%66, t = t0 + j - 1;
    xs[ci][j] = __float2bfloat16((t>=0 && t<512) ? x[(size_t)(n*64+ci)*512 + t] : 0.0f);
  }
  __syncthreads();
  const int co = tid & 63, tg = tid >> 6;
  float acc[16];
  { float bb = bias[co];
    #pragma unroll
    for (int i=0;i<16;i++) acc[i]=bb; }
  for (int ci=0; ci<64; ++ci) {
    const uint* xp = reinterpret_cast<const uint*>(&xs[ci][tg*16]);
    uint4 q0 = reinterpret_cast<const uint4*>(xp)[0];
    uint4 q1 = reinterpret_cast<const uint4*>(xp)[1];
    uint  u8 = xp[8];
    float xv[18] = { bf_lo(q0.x), bf_hi(q0.x), bf_lo(q0.y), bf_hi(q0.y),
                     bf_lo(q0.z), bf_hi(q0.z), bf_lo(q0.w), bf_hi(q0.w),
                     bf_lo(q1.x), bf_hi(q1.x), bf_lo(q1.y), bf_hi(q1.y),
                     bf_lo(q1.z), bf_hi(q1.z), bf_lo(q1.w), bf_hi(q1.w),
                     bf_lo(u8),   bf_hi(u8) };
    const float w0 = wsh[(ci*3+0)*65 + co];
    const float w1 = wsh[(ci*3+1)*65 + co];
    const float w2 = wsh[(ci*3+2)*65 + co];
    #pragma unroll
    for (int i=0;i<16;i++) acc[i] += w0*xv[i] + w1*xv[i+1] + w2*xv[i+2];
  }
  __hip_bfloat16* yp = &y[(size_t)(n*64+co)*512 + t0 + tg*16];
  #pragma unroll
  for (int i=0;i<16;i++) yp[i] = __float2bfloat16(acc[i]);
}

// ---------------- conv2: p1[2048][64][256] f32 -> y bf16 [2048][128][256] ----------------
__global__ __launch_bounds__(256) void conv2_kernel(
    const float* __restrict__ x, const float* __restrict__ w,
    const float* __restrict__ bias, __hip_bfloat16* __restrict__ y)
{
  __shared__ __hip_bfloat16 xs[64][40];    // rows 80B aligned
  __shared__ __hip_bfloat16 wsh[192*130];  // [ci*3+k][co] bf16
  const int n = blockIdx.y, t0 = blockIdx.x*32, tid = threadIdx.x;
  for (int i = tid; i < 128*192; i += 256) {
    int co = i/192, r = i%192;
    wsh[r*130 + co] = __float2bfloat16(w[i]);
  }
  for (int i = tid; i < 64*34; i += 256) {
    int ci = i/34, j = i%34, t = t0 + j - 1;
    xs[ci][j] = __float2bfloat16((t>=0 && t<256) ? x[(size_t)(n*64+ci)*256 + t] : 0.0f);
  }
  __syncthreads();
  const int co = tid & 127, tg = tid >> 7;
  float acc[16];
  { float bb = bias[co];
    #pragma unroll
    for (int i=0;i<16;i++) acc[i]=bb; }
  for (int ci=0; ci<64; ++ci) {
    const uint* xp = reinterpret_cast<const uint*>(&xs[ci][tg*16]);
    uint4 q0 = reinterpret_cast<const uint4*>(xp)[0];
    uint4 q1 = reinterpret_cast<const uint4*>(xp)[1];
    uint  u8 = xp[8];
    float xv[18] = { bf_lo(q0.x), bf_hi(q0.x), bf_lo(q0.y), bf_hi(q0.y),
                     bf_lo(q0.z), bf_hi(q0.z), bf_lo(q0.w), bf_hi(q0.w),
                     bf_lo(q1.x), bf_hi(q1.x), bf_lo(q1.y), bf_hi(q1.y),
                     bf_lo(q1.z), bf_hi(q1.z), bf_lo(q1.w), bf_hi(q1.w),
                     bf_lo(u8),   bf_hi(u8) };
    const float w0 = __bfloat162float(wsh[(ci*3+0)*130 + co]);
    const float w1 = __bfloat162float(wsh[(ci*3+1)*130 + co]);
    const float w2 = __bfloat162float(wsh[(ci*3+2)*130 + co]);
    #pragma unroll
    for (int i=0;i<16;i++) acc[i] += w0*xv[i] + w1*xv[i+1] + w2*xv[i+2];
  }
  __hip_bfloat16* yp = &y[(size_t)(n*128+co)*256 + t0 + tg*16];
  #pragma unroll
  for (int i=0;i<16;i++) yp[i] = __float2bfloat16(acc[i]);
}

// ---------------- BN stats (training mode, over N,T per channel) ----------------
__global__ __launch_bounds__(256) void bn_stats_kernel(
    const __hip_bfloat16* __restrict__ y, float* __restrict__ stat, int C, int T)
{
  const int c = blockIdx.x, n0 = blockIdx.y*64, tid = threadIdx.x;
  float s=0.f, q=0.f;
  const int per = T/256;
  for (int n=n0; n<n0+64; ++n) {
    const __hip_bfloat16* p = &y[(size_t)(n*C+c)*T];
    for (int r=0;r<per;r++){ float v = __bfloat162float(p[tid + r*256]); s+=v; q+=v*v; }
  }
  __shared__ float rs[256], rq[256];
  rs[tid]=s; rq[tid]=q; __syncthreads();
  for (int off=128; off>0; off>>=1){
    if (tid<off){ rs[tid]+=rs[tid+off]; rq[tid]+=rq[tid+off]; }
    __syncthreads();
  }
  if (tid==0){ atomicAdd(&stat[c], rs[0]); atomicAdd(&stat[128+c], rq[0]); }
}

__global__ void bn_finalize_kernel(float* __restrict__ stat, const float* __restrict__ g,
                                   const float* __restrict__ b, int C, float invCnt)
{
  int c = threadIdx.x;
  if (c < C) {
    float m  = stat[c]*invCnt;
    float v  = stat[128+c]*invCnt - m*m;
    float sc = g[c]*rsqrtf(v + 1e-5f);
    stat[256+c] = sc;
    stat[384+c] = b[c] - m*sc;
  }
}

// ---------------- BN apply + ReLU + maxpool2: y bf16 [N][C][2*Th] -> f32 [N][C][Th] ----------------
__global__ __launch_bounds__(256) void bn_pool_kernel(
    const __hip_bfloat16* __restrict__ y, const float* __restrict__ stat,
    float* __restrict__ outp, int C, int Th)
{
  const int idx = blockIdx.x*256 + threadIdx.x;
  const int c = (idx/Th)%C;
  uint u = reinterpret_cast<const uint*>(y)[idx];   // pair y[2t], y[2t+1]
  float sc = stat[256+c], sh = stat[384+c];
  float a  = fmaxf(sc*bf_lo(u)+sh, 0.f);
  float b2 = fmaxf(sc*bf_hi(u)+sh, 0.f);
  outp[idx] = fmaxf(a,b2);
}

// ---------------- transpose p2[n][128][128] -> s2[t][n][128] ----------------
__global__ __launch_bounds__(256) void transpose_kernel(const float* __restrict__ p2, float* __restrict__ s2)
{
  __shared__ float buf[128][65];
  const int n = blockIdx.x, t0 = blockIdx.y*64, tid = threadIdx.x;
  {
    const int tt = tid & 63, c0 = tid >> 6;
    for (int it=0; it<32; ++it) {
      int c = it*4 + c0;
      buf[c][tt] = p2[(size_t)(n*128+c)*128 + t0+tt];
    }
  }
  __syncthreads();
  {
    const int c = tid & 127, th = tid >> 7;
    for (int it=0; it<32; ++it) {
      int t = it*2 + th;
      s2[((size_t)(t0+t)*2048 + n)*128 + c] = buf[c][t];
    }
  }
}

// ---------------- whh -> bf16 gate-interleaved [d][h][4gt] ----------------
__global__ void whht_prep_kernel(const float* __restrict__ whf, const float* __restrict__ whr,
                                 __hip_bfloat16* __restrict__ whhT)
{
  const float* src = blockIdx.x ? whr : whf;
  __hip_bfloat16* dst = whhT + (size_t)blockIdx.x*65536;
  for (int i = threadIdx.x; i < 65536; i += 256) {
    int gt = i & 3, h = (i>>2)&127, d = i>>9;
    dst[i] = __float2bfloat16(src[(size_t)(gt*128+h)*128 + d]);
  }
}

// ---------------- input projection GEMM per chunk: pre[2][TC][2048][512] ----------------
// tile 128 rows x 128 gates, K=128 staged in quarters (LDS 33.8KB), thread 8x8.
__global__ __launch_bounds__(256) void inproj_kernel(
    const float* __restrict__ s2, const float* __restrict__ wf_, const float* __restrict__ wr_,
    const float* __restrict__ bf_, const float* __restrict__ br_,
    float* __restrict__ pre, int chunk)
{
  __shared__ float AsT[32][132];
  __shared__ float BsT[32][132];
  const int mt = blockIdx.x, gtile = blockIdx.y, dir = blockIdx.z, tid = threadIdx.x;
  const int tc = mt >> 4, n0 = (mt & 15)*128, g0 = gtile*128;
  const int tglob = chunk*TC + tc;
  const int tsrc  = dir ? (127 - tglob) : tglob;
  const float* wih  = dir ? wr_ : wf_;
  const float* bias = dir ? br_ : bf_;
  const float* aBase = s2 + ((size_t)tsrc*2048 + n0)*128;
  const int tx = tid & 15, ty = tid >> 4;
  float acc[8][8];
  {
    float bl[8];
    #pragma unroll
    for (int j=0;j<8;j++) bl[j] = bias[g0 + tx*8 + j];
    #pragma unroll
    for (int i=0;i<8;i++)
      #pragma unroll
      for (int j=0;j<8;j++) acc[i][j] = bl[j];
  }
  const int dd = tid & 31, rg = (tid >> 5)*16;
  for (int kq=0; kq<4; ++kq) {
    for (int r=0;r<16;r++) {
      AsT[dd][rg+r] = aBase[(size_t)(rg+r)*128 + kq*32 + dd];
      BsT[dd][rg+r] = wih[(size_t)(g0+rg+r)*128 + kq*32 + dd];
    }
    __syncthreads();
    for (int d2=0; d2<32; ++d2) {
      const float4 a0 = *reinterpret_cast<const float4*>(&AsT[d2][ty*8]);
      const float4 a1 = *reinterpret_cast<const float4*>(&AsT[d2][ty*8+4]);
      const float4 b0 = *reinterpret_cast<const float4*>(&BsT[d2][tx*8]);
      const float4 b1 = *reinterpret_cast<const float4*>(&BsT[d2][tx*8+4]);
      const float av[8] = {a0.x,a0.y,a0.z,a0.w,a1.x,a1.y,a1.z,a1.w};
      const float bv[8] = {b0.x,b0.y,b0.z,b0.w,b1.x,b1.y,b1.z,b1.w};
      #pragma unroll
      for (int i=0;i<8;i++)
        #pragma unroll
        for (int j=0;j<8;j++) acc[i][j] += av[i]*bv[j];
    }
    __syncthreads();
  }
  float* pBase = pre + ((size_t)(dir*TC + tc)*2048 + n0 + ty*8)*512 + g0 + tx*8;
  #pragma unroll
  for (int i=0;i<8;i++) {
    *reinterpret_cast<float4*>(pBase + (size_t)i*512)     = make_float4(acc[i][0],acc[i][1],acc[i][2],acc[i][3]);
    *reinterpret_cast<float4*>(pBase + (size_t)i*512 + 4) = make_float4(acc[i][4],acc[i][5],acc[i][6],acc[i][7]);
  }
}

// ---------------- LSTM recurrence: 16 nodes/block, whh bf16 in 128KB LDS ----------------
// thread = 4 nodes x 2 hidx x 4 gates (32 acc). LDS reads all conflict-free
// (weights contiguous 16B/lane, h broadcast b128).
__global__ __launch_bounds__(256) void lstm_chunk_kernel(
    const float* __restrict__ pre, const __hip_bfloat16* __restrict__ whhT,
    float* __restrict__ hstate, float* __restrict__ cstate, float* __restrict__ hsum)
{
  extern __shared__ char smem[];
  __hip_bfloat16* wl = reinterpret_cast<__hip_bfloat16*>(smem);   // [128d][128h][4gt] = 131072B
  float* hb = reinterpret_cast<float*>(smem + 131072);            // [16][128] f32
  const int dir = blockIdx.y, n0 = blockIdx.x*16, tid = threadIdx.x;
  {
    const uint4* src = reinterpret_cast<const uint4*>(whhT + (size_t)dir*65536);
    uint4* dst = reinterpret_cast<uint4*>(wl);
    for (int i=tid; i<8192; i+=256) dst[i] = src[i];
  }
  float* hsG = hstate + (size_t)(dir*2048 + n0)*128;
  for (int i=tid; i<2048; i+=256) hb[i] = hsG[i];
  const int hbi = (tid & 63)*2;
  const int nd  = (tid >> 6)*4;
  float cst[4][2], hacc[4][2];
  float* cG = cstate + (size_t)(dir*2048 + n0)*128;
  #pragma unroll
  for (int j=0;j<4;j++){
    float2 cv = *reinterpret_cast<const float2*>(&cG[(nd+j)*128 + hbi]);
    cst[j][0]=cv.x; cst[j][1]=cv.y; hacc[j][0]=0.f; hacc[j][1]=0.f;
  }
  __syncthreads();
  for (int t=0; t<TC; ++t) {
    const float* pb = pre + ((size_t)(dir*TC + t)*2048 + n0)*512;
    float acc[4][4][2];
    #pragma unroll
    for (int j=0;j<4;j++)
      #pragma unroll
      for (int g=0; g<4; ++g) {
        float2 pv = *reinterpret_cast<const float2*>(&pb[(size_t)(nd+j)*512 + g*128 + hbi]);
        acc[j][g][0]=pv.x; acc[j][g][1]=pv.y;
      }
    for (int dq=0; dq<32; ++dq) {
      float4 hq[4];
      #pragma unroll
      for (int j=0;j<4;j++) hq[j] = *reinterpret_cast<const float4*>(&hb[(nd+j)*128 + dq*4]);
      #pragma unroll
      for (int dd=0; dd<4; ++dd) {
        const int d = dq*4 + dd;
        uint4 wv = *reinterpret_cast<const uint4*>(&wl[(size_t)(d*128 + hbi)*4]);
        float wf[8] = { bf_lo(wv.x), bf_hi(wv.x), bf_lo(wv.y), bf_hi(wv.y),
                        bf_lo(wv.z), bf_hi(wv.z), bf_lo(wv.w), bf_hi(wv.w) };
        #pragma unroll
        for (int j=0;j<4;j++) {
          const float hv = (&hq[j].x)[dd];
          #pragma unroll
          for (int g=0; g<4; ++g) {
            acc[j][g][0] += hv*wf[g];
            acc[j][g][1] += hv*wf[4+g];
          }
        }
      }
    }
    __syncthreads();
    #pragma unroll
    for (int j=0;j<4;j++) {
      #pragma unroll
      for (int hi=0; hi<2; ++hi) {
        float ig = sigmoidf_(acc[j][0][hi]);
        float fg = sigmoidf_(acc[j][1][hi]);
        float gg = tanhf_(acc[j][2][hi]);
        float og = sigmoidf_(acc[j][3][hi]);
        float cv = fg*cst[j][hi] + ig*gg;
        cst[j][hi] = cv;
        float hv = og*tanhf_(cv);
        hacc[j][hi] += hv;
        hb[(nd+j)*128 + hbi + hi] = hv;
      }
    }
    __syncthreads();
  }
  for (int i=tid; i<2048; i+=256) hsG[i] = hb[i];
  #pragma unroll
  for (int j=0;j<4;j++)
    *reinterpret_cast<float2*>(&cG[(nd+j)*128 + hbi]) = make_float2(cst[j][0], cst[j][1]);
  float* hmG = hsum + (size_t)(dir*2048 + n0)*128;
  #pragma unroll
  for (int j=0;j<4;j++){
    float2 o = *reinterpret_cast<const float2*>(&hmG[(nd+j)*128 + hbi]);
    *reinterpret_cast<float2*>(&hmG[(nd+j)*128 + hbi]) = make_float2(o.x + hacc[j][0], o.y + hacc[j][1]);
  }
}

// ---------------- feats = mean over T of [hf, hr] ----------------
__global__ __launch_bounds__(256) void feats_kernel(const float* __restrict__ hsum, float* __restrict__ feats)
{
  int idx = blockIdx.x*256 + threadIdx.x;
  int k = idx & 255, n = idx >> 8;
  float v = (k<128) ? hsum[(size_t)n*128 + k]
                    : hsum[(size_t)2048*128 + (size_t)n*128 + (k-128)];
  feats[idx] = v * 0.0078125f;
}

// ---------------- Wh = in @ W^T  ([2048,K] x [128,K]) ----------------
template<int K>
__global__ __launch_bounds__(256) void node_gemm_kernel(
    const float* __restrict__ inp, const float* __restrict__ W, float* __restrict__ outp)
{
  __shared__ float ft[32][K];
  const int i0 = blockIdx.x*32, tid = threadIdx.x;
  for (int i=tid; i<32*K; i+=256) ft[i/K][i%K] = inp[(size_t)i0*K + i];
  __syncthreads();
  const int f = tid & 127, ih = (tid >> 7)*16;
  float acc[16];
  #pragma unroll
  for (int ii=0;ii<16;ii++) acc[ii]=0.f;
  const float* wp = W + (size_t)f*K;
  for (int k=0;k<K;k+=4) {
    const float4 wv = *reinterpret_cast<const float4*>(&wp[k]);
    #pragma unroll
    for (int ii=0;ii<16;ii++) {
      const float* fp = &ft[ih+ii][k];
      acc[ii] += fp[0]*wv.x + fp[1]*wv.y + fp[2]*wv.z + fp[3]*wv.w;
    }
  }
  #pragma unroll
  for (int ii=0;ii<16;ii++) outp[(size_t)(i0+ih+ii)*128 + f] = acc[ii];
}

// ---------------- s1/s2 per node (dot with attention vector halves) ----------------
__global__ __launch_bounds__(256) void gat_s_kernel(const float* __restrict__ Wh,
    const float* __restrict__ a, float* __restrict__ s1, float* __restrict__ s2)
{
  const int node = blockIdx.x*4 + (threadIdx.x >> 6);
  const int l = threadIdx.x & 63;
  const float w0 = Wh[(size_t)node*128 + l], w1 = Wh[(size_t)node*128 + 64 + l];
  float v1 = w0*a[l]     + w1*a[64+l];
  float v2 = w0*a[128+l] + w1*a[192+l];
  #pragma unroll
  for (int off=32; off>0; off>>=1){ v1 += __shfl_down(v1, off); v2 += __shfl_down(v2, off); }
  if (l==0){ s1[node]=v1; s2[node]=v2; }
}

// ---------------- GAT attention row: softmax(masked lrelu(s1_i+s2_j)) @ Wh ----------------
__global__ __launch_bounds__(256) void gat_attn_kernel(const float* __restrict__ Wh,
    const float* __restrict__ s1, const float* __restrict__ s2v,
    const int* __restrict__ adj, float* __restrict__ outp, int applyElu)
{
  __shared__ float ebuf[2048];
  __shared__ float red[256];
  const int i = blockIdx.x, tid = threadIdx.x;
  const float s1i = s1[i];
  const int* arow = adj + (size_t)i*2048;
  float ev[8]; float lmax = -3.0e38f;
  #pragma unroll
  for (int r=0;r<8;r++){
    int j = tid + r*256;
    float e = s1i + s2v[j];
    e = (e>0.f) ? e : 0.2f*e;
    e = (arow[j] > 0) ? e : -3.0e38f;     // exp underflows to 0; all-masked row -> uniform (matches ref)
    ev[r]=e; lmax = fmaxf(lmax,e);
  }
  red[tid]=lmax; __syncthreads();
  for (int off=128; off>0; off>>=1){ if (tid<off) red[tid]=fmaxf(red[tid],red[tid+off]); __syncthreads(); }
  const float m = red[0]; __syncthreads();
  float lsum=0.f;
  #pragma unroll
  for (int r=0;r<8;r++){ float p = __expf(ev[r]-m); ebuf[tid+r*256]=p; lsum+=p; }
  red[tid]=lsum; __syncthreads();
  for (int off=128; off>0; off>>=1){ if (tid<off) red[tid]+=red[tid+off]; __syncthreads(); }
  const float inv = 1.0f/red[0];
  __syncthreads();
  const int f = tid & 127, jh = tid >> 7;
  float acc=0.f;
  for (int j=0;j<1024;j++) acc += ebuf[jh*1024 + j] * Wh[(size_t)(jh*1024 + j)*128 + f];
  red[tid]=acc; __syncthreads();
  if (tid<128){
    float v = (red[tid]+red[tid+128])*inv;
    if (applyElu) v = (v>0.f) ? v : (__expf(v)-1.0f);
    outp[(size_t)i*128 + tid] = v;
  }
}

// ---------------- launch ----------------
extern "C" void kernel_launch(void* const* d_in, const int* in_sizes, int n_in,
                              void* d_out, int out_size, void* d_ws, size_t ws_size,
                              hipStream_t stream)
{
  (void)in_sizes; (void)n_in; (void)out_size; (void)ws_size;
  const float* x    = (const float*)d_in[0];
  const int*   adj  = (const int*)d_in[1];
  const float* c1w  = (const float*)d_in[2];
  const float* c1b  = (const float*)d_in[3];
  const float* bn1g = (const float*)d_in[4];
  const float* bn1b = (const float*)d_in[5];
  const float* c2w  = (const float*)d_in[6];
  const float* c2b  = (const float*)d_in[7];
  const float* bn2g = (const float*)d_in[8];
  const float* bn2b = (const float*)d_in[9];
  const float* wif  = (const float*)d_in[10];
  const float* whf  = (const float*)d_in[11];
  const float* bfv  = (const float*)d_in[12];
  const float* wir  = (const float*)d_in[13];
  const float* whr  = (const float*)d_in[14];
  const float* brv  = (const float*)d_in[15];
  const float* g1W  = (const float*)d_in[16];
  const float* g1a  = (const float*)d_in[17];
  const float* g2W  = (const float*)d_in[18];
  const float* g2a  = (const float*)d_in[19];
  float* outp = (float*)d_out;
  float* ws   = (float*)d_ws;

  __hip_bfloat16* bufY  = (__hip_bfloat16*)(ws + OFF_A);
  float* bufS2 = ws + OFF_A;
  float* bufP  = ws + OFF_B;
  float* bufPre= ws + OFF_B;
  __hip_bfloat16* whhT = (__hip_bfloat16*)(ws + OFF_WHHT);
  float* hst  = ws + OFF_H;
  float* cstG = ws + OFF_C;
  float* hsm  = ws + OFF_HSUM;
  float* feats= ws + OFF_FEAT;
  float* Wh1  = ws + OFF_WH1;
  float* s1a  = ws + OFF_S1A;
  float* s2a  = ws + OFF_S2A;
  float* h1   = ws + OFF_H1;
  float* Wh2  = ws + OFF_WH2;
  float* s1b  = ws + OFF_S1B;
  float* s2b  = ws + OFF_S2B;
  float* stat = ws + OFF_STAT;

  // zero states (h, c, hsum are contiguous) and BN stat accumulators every call
  hipMemsetAsync(hst, 0, (size_t)3*524288*sizeof(float), stream);
  hipMemsetAsync(stat, 0, 512*sizeof(float), stream);

  // conv1 -> BN -> relu -> pool
  conv1_kernel<<<dim3(8,2048),256,0,stream>>>(x, c1w, c1b, bufY);
  bn_stats_kernel<<<dim3(64,32),256,0,stream>>>(bufY, stat, 64, 512);
  bn_finalize_kernel<<<1,128,0,stream>>>(stat, bn1g, bn1b, 64, 1.0f/(2048.0f*512.0f));
  bn_pool_kernel<<<131072,256,0,stream>>>(bufY, stat, bufP, 64, 256);

  // conv2 -> BN -> relu -> pool
  hipMemsetAsync(stat, 0, 256*sizeof(float), stream);
  conv2_kernel<<<dim3(8,2048),256,0,stream>>>(bufP, c2w, c2b, bufY);
  bn_stats_kernel<<<dim3(128,32),256,0,stream>>>(bufY, stat, 128, 256);
  bn_finalize_kernel<<<1,128,0,stream>>>(stat, bn2g, bn2b, 128, 1.0f/(2048.0f*256.0f));
  bn_pool_kernel<<<131072,256,0,stream>>>(bufY, stat, bufP, 128, 128);

  // seq layout + LSTM
  transpose_kernel<<<dim3(2048,2),256,0,stream>>>(bufP, bufS2);
  whht_prep_kernel<<<2,256,0,stream>>>(whf, whr, whhT);
  hipFuncSetAttribute((const void*)lstm_chunk_kernel,
                      hipFuncAttributeMaxDynamicSharedMemorySize, 139264);
  for (int ch=0; ch<8; ++ch) {
    inproj_kernel<<<dim3(256,4,2),256,0,stream>>>(bufS2, wif, wir, bfv, brv, bufPre, ch);
    lstm_chunk_kernel<<<dim3(128,2),256,139264,stream>>>(bufPre, whhT, hst, cstG, hsm);
  }
  feats_kernel<<<2048,256,0,stream>>>(hsm, feats);

  // GAT x2
  node_gemm_kernel<256><<<64,256,0,stream>>>(feats, g1W, Wh1);
  gat_s_kernel<<<512,256,0,stream>>>(Wh1, g1a, s1a, s2a);
  gat_attn_kernel<<<2048,256,0,stream>>>(Wh1, s1a, s2a, adj, h1, 1);
  node_gemm_kernel<128><<<64,256,0,stream>>>(h1, g2W, Wh2);
  gat_s_kernel<<<512,256,0,stream>>>(Wh2, g2a, s1b, s2b);
  gat_attn_kernel<<<2048,256,0,stream>>>(Wh2, s1b, s2b, adj, outp, 0);
}

// Round 3
// 1615.818 us; speedup vs baseline: 2.5925x; 2.5925x over previous
//
#include <hip/hip_runtime.h>

typedef unsigned int uint;
#define DI __device__ __forceinline__

typedef __bf16 bf16;
typedef __attribute__((ext_vector_type(4))) float f32x4;
typedef __attribute__((ext_vector_type(8))) __bf16 bf16x8;
typedef __attribute__((ext_vector_type(4))) int i32x4;

// ---------------- ws layout (float units) ----------------
constexpr size_t OFF_A    = 0;                    // 33,554,432 f: y1/y2 bf16 [N][C][T]
constexpr size_t OFF_B    = 33554432;             // 33,554,432 f: xpose-pool outputs + pre
constexpr size_t OFF_B1   = OFF_B + 16777216;     // upper half of B
constexpr size_t OFF_WHHG = 67108864;             // bf16 [2][512][128]  (65,536 f)
constexpr size_t OFF_WIHG = OFF_WHHG + 65536;     // bf16 [2][512][128]  (65,536 f)
constexpr size_t OFF_BIAS = OFF_WIHG + 65536;     // f32 [2][512]        (1,024 f)
constexpr size_t OFF_H    = OFF_BIAS + 1024;      // bf16 [2][2048][128] (262,144 f)
constexpr size_t OFF_C    = OFF_H + 262144;       // f32 [2][2048][128]
constexpr size_t OFF_HSUM = OFF_C + 524288;       // f32 [2][2048][128]
constexpr size_t OFF_FEAT = OFF_HSUM + 524288;    // f32 [2048][256]
constexpr size_t OFF_WH1  = OFF_FEAT + 524288;    // f32 [2048][128]
constexpr size_t OFF_S1A  = OFF_WH1 + 262144;
constexpr size_t OFF_S2A  = OFF_S1A + 2048;
constexpr size_t OFF_H1   = OFF_S2A + 2048;
constexpr size_t OFF_WH2  = OFF_H1 + 262144;
constexpr size_t OFF_S1B  = OFF_WH2 + 262144;
constexpr size_t OFF_S2B  = OFF_S1B + 2048;
constexpr size_t OFF_STAT = OFF_S2B + 2048;       // sum[128] sumsq[128] scale[128] shift[128]
// total ~69.9M floats = 279.5 MB (<= R2's footprint which passed)

DI float bflo(uint u){ union { uint i; float f; } v; v.i = u << 16;         return v.f; }
DI float bfhi(uint u){ union { uint i; float f; } v; v.i = u & 0xffff0000u; return v.f; }
DI float sigmoidf_(float x){ return 1.0f/(1.0f + __expf(-x)); }
DI float tanhf_(float x){ float e = __expf(-2.0f*fabsf(x)); float r = (1.0f-e)/(1.0f+e); return x>=0.0f ? r : -r; }

DI f32x4 mfma16(i32x4 a, i32x4 b, f32x4 c){
  return __builtin_amdgcn_mfma_f32_16x16x32_bf16(
      __builtin_bit_cast(bf16x8, a), __builtin_bit_cast(bf16x8, b), c, 0, 0, 0);
}

// swizzled LDS address helpers (rows of 128B / 256B, XOR bits[4:6] by row&7)
DI char* swz128(char* base, int row, int byteInRow){ return base + row*128 + (byteInRow ^ ((row&7)<<4)); }
DI char* swz256(char* base, int row, int byteInRow){ return base + row*256 + (byteInRow ^ ((row&7)<<4)); }

// ---------------- prep: gate-interleaved bf16 weights ----------------
// c = hh*4 + gate ; src row = gate*128 + hh
__global__ void prep_kernel(const float* __restrict__ whf, const float* __restrict__ whr,
                            const float* __restrict__ wif, const float* __restrict__ wir,
                            const float* __restrict__ bfv, const float* __restrict__ brv,
                            bf16* __restrict__ whh_g, bf16* __restrict__ wih_g,
                            float* __restrict__ bias_g)
{
  const int dir = blockIdx.y;
  const float* whh = dir ? whr : whf;
  const float* wih = dir ? wir : wif;
  const float* bb  = dir ? brv : bfv;
  int idx = blockIdx.x*256 + threadIdx.x;        // < 65536
  int c = idx >> 7, d = idx & 127;
  int src = ((c & 3)*128 + (c >> 2))*128 + d;
  whh_g[(size_t)dir*65536 + idx] = (bf16)whh[src];
  wih_g[(size_t)dir*65536 + idx] = (bf16)wih[src];
  if (idx < 512) bias_g[dir*512 + idx] = bb[(idx & 3)*128 + (idx >> 2)];
}

// ---------------- conv1: x f32 [2048][64][512] -> y1 bf16 [2048][64][512] ----------------
// 3 shifted GEMMs (K=64/tap), M-tile 256 t, N=64 co. 512 thr = 8 waves (4m x 2c).
__global__ __launch_bounds__(512) void conv1_kernel(
    const float* __restrict__ x, const float* __restrict__ w,
    const float* __restrict__ bias, bf16* __restrict__ y)
{
  __shared__ bf16 xa[258*64];     // [row=t-t0+1][ci], 128B rows, swizzled
  __shared__ bf16 wb[3*64*64];    // [dk*64+co][ci], swizzled
  const int n = blockIdx.y, t0 = blockIdx.x*256, tid = threadIdx.x;
  for (int i = tid; i < 12288; i += 512) {
    int ci = i & 63, co = (i >> 6) & 63, dk = i >> 12;
    int row = dk*64 + co;
    *(bf16*)swz128((char*)wb, row, ci*2) = (bf16)w[(co*64 + ci)*3 + dk];
  }
  for (int i = tid; i < 16384; i += 512) {
    int tt = i & 255, ci = i >> 8;
    int row = tt + 1;
    *(bf16*)swz128((char*)xa, row, ci*2) = (bf16)x[((size_t)n*64 + ci)*512 + t0 + tt];
  }
  if (tid < 128) {
    int ci = tid >> 1, e = tid & 1;
    int row = e ? 257 : 0;
    int t = t0 + (e ? 256 : -1);
    float v = (t >= 0 && t < 512) ? x[((size_t)n*64 + ci)*512 + t] : 0.0f;
    *(bf16*)swz128((char*)xa, row, ci*2) = (bf16)v;
  }
  __syncthreads();
  const int lane = tid & 63, wv = tid >> 6;
  const int m0 = (wv & 3)*64, c0 = (wv >> 2)*32;
  const int l15 = lane & 15, lh = lane >> 4;
  f32x4 acc[4][2];
  #pragma unroll
  for (int mf = 0; mf < 4; ++mf)
    #pragma unroll
    for (int cf = 0; cf < 2; ++cf) {
      float bb = bias[c0 + cf*16 + l15];
      acc[mf][cf] = (f32x4){bb, bb, bb, bb};
    }
  #pragma unroll
  for (int dk = 0; dk < 3; ++dk)
    #pragma unroll
    for (int ks = 0; ks < 2; ++ks) {
      const int kb = ks*64 + lh*16;
      i32x4 bfr[2], afr[4];
      #pragma unroll
      for (int cf = 0; cf < 2; ++cf) {
        int row = dk*64 + c0 + cf*16 + l15;
        bfr[cf] = *(const i32x4*)swz128((char*)wb, row, kb);
      }
      #pragma unroll
      for (int mf = 0; mf < 4; ++mf) {
        int row = m0 + mf*16 + l15 + dk;
        afr[mf] = *(const i32x4*)swz128((char*)xa, row, kb);
      }
      #pragma unroll
      for (int mf = 0; mf < 4; ++mf)
        #pragma unroll
        for (int cf = 0; cf < 2; ++cf)
          acc[mf][cf] = mfma16(afr[mf], bfr[cf], acc[mf][cf]);
    }
  #pragma unroll
  for (int mf = 0; mf < 4; ++mf)
    #pragma unroll
    for (int cf = 0; cf < 2; ++cf) {
      int co = c0 + cf*16 + l15;
      int tt = t0 + m0 + mf*16 + lh*4;
      union { bf16 h[4]; uint2 u; } pk;
      #pragma unroll
      for (int r = 0; r < 4; ++r) pk.h[r] = (bf16)acc[mf][cf][r];
      *(uint2*)&y[((size_t)n*64 + co)*512 + tt] = pk.u;
    }
}

// ---------------- conv2: pool1T bf16 [2048][256][64] -> y2 bf16 [2048][128][256] ----------------
__global__ __launch_bounds__(512) void conv2_kernel(
    const bf16* __restrict__ xin, const float* __restrict__ w,
    const float* __restrict__ bias, bf16* __restrict__ y)
{
  __shared__ bf16 xa[258*64];
  __shared__ bf16 wb[3*128*64];
  const int n = blockIdx.x, tid = threadIdx.x;
  for (int i = tid; i < 24576; i += 512) {
    int ci = i & 63, co = (i >> 6) & 127, dk = i >> 13;
    int row = dk*128 + co;
    *(bf16*)swz128((char*)wb, row, ci*2) = (bf16)w[(co*64 + ci)*3 + dk];
  }
  { // x core rows 1..256, linear uint4 copy with swizzled dest
    const i32x4* src = (const i32x4*)(xin + (size_t)n*256*64);
    for (int i = tid; i < 2048; i += 512) {
      int row = (i >> 3) + 1, blk = i & 7;
      *(i32x4*)swz128((char*)xa, row, blk*16) = src[i];
    }
  }
  if (tid < 128) {
    int ci = tid >> 1, e = tid & 1;
    int row = e ? 257 : 0;
    *(bf16*)swz128((char*)xa, row, ci*2) = (bf16)0.0f;   // both halos OOB -> zero
  }
  __syncthreads();
  const int lane = tid & 63, wv = tid >> 6;
  const int m0 = (wv & 3)*64, c0 = (wv >> 2)*64;
  const int l15 = lane & 15, lh = lane >> 4;
  f32x4 acc[4][4];
  #pragma unroll
  for (int mf = 0; mf < 4; ++mf)
    #pragma unroll
    for (int cf = 0; cf < 4; ++cf) {
      float bb = bias[c0 + cf*16 + l15];
      acc[mf][cf] = (f32x4){bb, bb, bb, bb};
    }
  #pragma unroll
  for (int dk = 0; dk < 3; ++dk)
    #pragma unroll
    for (int ks = 0; ks < 2; ++ks) {
      const int kb = ks*64 + lh*16;
      i32x4 bfr[4], afr[4];
      #pragma unroll
      for (int cf = 0; cf < 4; ++cf) {
        int row = dk*128 + c0 + cf*16 + l15;
        bfr[cf] = *(const i32x4*)swz128((char*)wb, row, kb);
      }
      #pragma unroll
      for (int mf = 0; mf < 4; ++mf) {
        int row = m0 + mf*16 + l15 + dk;
        afr[mf] = *(const i32x4*)swz128((char*)xa, row, kb);
      }
      #pragma unroll
      for (int mf = 0; mf < 4; ++mf)
        #pragma unroll
        for (int cf = 0; cf < 4; ++cf)
          acc[mf][cf] = mfma16(afr[mf], bfr[cf], acc[mf][cf]);
    }
  #pragma unroll
  for (int mf = 0; mf < 4; ++mf)
    #pragma unroll
    for (int cf = 0; cf < 4; ++cf) {
      int co = c0 + cf*16 + l15;
      int tt = m0 + mf*16 + lh*4;
      union { bf16 h[4]; uint2 u; } pk;
      #pragma unroll
      for (int r = 0; r < 4; ++r) pk.h[r] = (bf16)acc[mf][cf][r];
      *(uint2*)&y[((size_t)n*128 + co)*256 + tt] = pk.u;
    }
}

// ---------------- BN stats (training mode, over N,T per channel) ----------------
__global__ __launch_bounds__(256) void bn_stats_kernel(
    const bf16* __restrict__ y, float* __restrict__ stat, int C, int T)
{
  const int c = blockIdx.x, n0 = blockIdx.y*64, tid = threadIdx.x;
  float s = 0.f, q = 0.f;
  const int per = T/256;
  for (int n = n0; n < n0 + 64; ++n) {
    const bf16* p = &y[(size_t)(n*C + c)*T];
    for (int r = 0; r < per; ++r) { float v = (float)p[tid + r*256]; s += v; q += v*v; }
  }
  __shared__ float rs[256], rq[256];
  rs[tid] = s; rq[tid] = q; __syncthreads();
  for (int off = 128; off > 0; off >>= 1) {
    if (tid < off) { rs[tid] += rs[tid+off]; rq[tid] += rq[tid+off]; }
    __syncthreads();
  }
  if (tid == 0) { atomicAdd(&stat[c], rs[0]); atomicAdd(&stat[128+c], rq[0]); }
}

__global__ void bn_finalize_kernel(float* __restrict__ stat, const float* __restrict__ g,
                                   const float* __restrict__ b, int C, float invCnt)
{
  int c = threadIdx.x;
  if (c < C) {
    float m  = stat[c]*invCnt;
    float v  = stat[128+c]*invCnt - m*m;
    float sc = g[c]*rsqrtf(v + 1e-5f);
    stat[256+c] = sc;
    stat[384+c] = b[c] - m*sc;
  }
}

// ---------------- BN apply + ReLU + maxpool2 + transpose: [n][C][2*TH] -> bf16 [n][TH][C] ----------------
template<int C, int TH>
__global__ __launch_bounds__(256) void poolT_kernel(
    const bf16* __restrict__ yin, const float* __restrict__ stat, bf16* __restrict__ outp)
{
  __shared__ bf16 buf[C][TH + 2];
  const int n = blockIdx.x, tid = threadIdx.x;
  const uint* src = (const uint*)(yin + (size_t)n*C*TH*2);
  for (int i = tid; i < C*TH; i += 256) {
    int th = i & (TH - 1), c = i / TH;
    uint u = src[i];
    float sc = stat[256 + c], sh = stat[384 + c];
    float a = fmaxf(sc*bflo(u) + sh, 0.f);
    float b = fmaxf(sc*bfhi(u) + sh, 0.f);
    buf[c][th] = (bf16)fmaxf(a, b);
  }
  __syncthreads();
  bf16* dst = outp + (size_t)n*TH*C;
  for (int i = tid; i < TH*C/2; i += 256) {
    int cp = i & (C/2 - 1), th = i / (C/2);
    union { bf16 h[2]; uint u; } pk;
    pk.h[0] = buf[2*cp][th]; pk.h[1] = buf[2*cp + 1][th];
    *(uint*)&dst[th*C + 2*cp] = pk.u;
  }
}

// ---------------- input projection: pool2T [2048][128t][128c] @ wih_gi -> pre bf16 [2][16][512][2048] ----------------
__global__ __launch_bounds__(256) void inproj_kernel(
    const bf16* __restrict__ p2t, const bf16* __restrict__ wih_g,
    const float* __restrict__ bias_g, bf16* __restrict__ pre, int chunk)
{
  __shared__ bf16 As[128*128];   // rows n, 256B, swizzled
  __shared__ bf16 Bs[128*128];   // rows c, 256B, swizzled
  const int mt = blockIdx.x, ct = blockIdx.y, z = blockIdx.z;
  const int dir = z >> 4, tl = z & 15;
  const int tg = chunk*16 + tl;
  const int tsrc = dir ? (127 - tg) : tg;
  const int n0 = mt*128, c0 = ct*128, tid = threadIdx.x;
  const bf16* wsrc = wih_g + ((size_t)dir*512 + c0)*128;
  for (int i = tid; i < 2048; i += 256) {
    int row = i >> 4, blk = i & 15;
    i32x4 av = *(const i32x4*)(p2t + ((size_t)(n0 + row)*128 + tsrc)*128 + blk*8);
    *(i32x4*)swz256((char*)As, row, blk*16) = av;
    i32x4 bv = *(const i32x4*)(wsrc + (size_t)row*128 + blk*8);
    *(i32x4*)swz256((char*)Bs, row, blk*16) = bv;
  }
  __syncthreads();
  const int lane = tid & 63, wv = tid >> 6;
  const int m0 = (wv & 1)*64, cc0 = (wv >> 1)*64;
  const int l15 = lane & 15, lh = lane >> 4;
  f32x4 acc[4][4];
  #pragma unroll
  for (int mf = 0; mf < 4; ++mf)
    #pragma unroll
    for (int cf = 0; cf < 4; ++cf) {
      float bb = bias_g[dir*512 + c0 + cc0 + cf*16 + l15];
      acc[mf][cf] = (f32x4){bb, bb, bb, bb};
    }
  #pragma unroll
  for (int ks = 0; ks < 4; ++ks) {
    const int kb = ks*64 + lh*16;
    i32x4 afr[4], bfr[4];
    #pragma unroll
    for (int mf = 0; mf < 4; ++mf) {
      int row = m0 + mf*16 + l15;
      afr[mf] = *(const i32x4*)swz256((char*)As, row, kb);
    }
    #pragma unroll
    for (int cf = 0; cf < 4; ++cf) {
      int row = cc0 + cf*16 + l15;
      bfr[cf] = *(const i32x4*)swz256((char*)Bs, row, kb);
    }
    #pragma unroll
    for (int mf = 0; mf < 4; ++mf)
      #pragma unroll
      for (int cf = 0; cf < 4; ++cf)
        acc[mf][cf] = mfma16(afr[mf], bfr[cf], acc[mf][cf]);
  }
  #pragma unroll
  for (int mf = 0; mf < 4; ++mf)
    #pragma unroll
    for (int cf = 0; cf < 4; ++cf) {
      int cc = c0 + cc0 + cf*16 + l15;
      int nn = n0 + m0 + mf*16 + lh*4;
      union { bf16 h[4]; uint2 u; } pk;
      #pragma unroll
      for (int r = 0; r < 4; ++r) pk.h[r] = (bf16)acc[mf][cf][r];
      *(uint2*)&pre[(((size_t)(dir*16 + tl)*512 + cc)*2048) + nn] = pk.u;
    }
}

// ---------------- LSTM recurrence: MFMA, whh in registers, h bf16 in 4KB LDS ----------------
// block = 16 nodes, 4 waves (wave w owns gate-cols [w*128, w*128+128) = hh [w*32, w*32+32))
__global__ __launch_bounds__(256) void lstm_kernel(
    const bf16* __restrict__ pre, const bf16* __restrict__ whh_g,
    bf16* __restrict__ hstate, float* __restrict__ cstate, float* __restrict__ hsum)
{
  __shared__ bf16 hb[2048];   // [16 n][128 k], 256B rows, swizzled
  const int dir = blockIdx.y, n0 = blockIdx.x*16, tid = threadIdx.x;
  const int lane = tid & 63, wv = tid >> 6;
  const int l15 = lane & 15, lh = lane >> 4;
  i32x4 bfr[8][4];
  const bf16* wbase = whh_g + (size_t)dir*65536;
  #pragma unroll
  for (int cf = 0; cf < 8; ++cf) {
    int c = wv*128 + cf*16 + l15;
    #pragma unroll
    for (int ks = 0; ks < 4; ++ks)
      bfr[cf][ks] = *(const i32x4*)(wbase + (size_t)c*128 + ks*32 + lh*8);
  }
  bf16* hsG = hstate + ((size_t)dir*2048 + n0)*128;
  {
    int nn = tid >> 4, kb = tid & 15;
    i32x4 v = *(const i32x4*)(hsG + nn*128 + kb*8);
    *(i32x4*)swz256((char*)hb, nn, kb*16) = v;
  }
  const int nd2 = (lh << 2) + (lane & 3);
  const int hhq = (lane >> 2) & 3;
  const int p = lane & 3;
  float creg[8], hac[8];
  float* cG = cstate + ((size_t)dir*2048 + n0)*128;
  #pragma unroll
  for (int cf = 0; cf < 8; ++cf) {
    int hh = wv*32 + cf*4 + hhq;
    creg[cf] = cG[nd2*128 + hh];
    hac[cf] = 0.f;
  }
  __syncthreads();
  const bf16* preB = pre + (size_t)dir*16*512*2048;
  for (int t = 0; t < 16; ++t) {
    f32x4 acc[8];
    #pragma unroll
    for (int cf = 0; cf < 8; ++cf) {
      int c = wv*128 + cf*16 + l15;
      uint2 pv = *(const uint2*)(preB + ((size_t)t*512 + c)*2048 + n0 + (lh << 2));
      acc[cf] = (f32x4){ bflo(pv.x), bfhi(pv.x), bflo(pv.y), bfhi(pv.y) };
    }
    i32x4 af[4];
    #pragma unroll
    for (int ks = 0; ks < 4; ++ks)
      af[ks] = *(const i32x4*)swz256((char*)hb, l15, ks*64 + lh*16);
    #pragma unroll
    for (int cf = 0; cf < 8; ++cf)
      #pragma unroll
      for (int ks = 0; ks < 4; ++ks)
        acc[cf] = mfma16(af[ks], bfr[cf][ks], acc[cf]);
    __syncthreads();   // all waves done reading h(t-1)
    #pragma unroll
    for (int cf = 0; cf < 8; ++cf) {
      float v0 = acc[cf][0], v1 = acc[cf][1], v2 = acc[cf][2], v3 = acc[cf][3];
      // quad butterfly transpose: reg index (node) <-> lane&3 (gate)
      float s01 = (p & 1) ? v0 : v1; float r01 = __shfl_xor(s01, 1);
      float s23 = (p & 1) ? v2 : v3; float r23 = __shfl_xor(s23, 1);
      float w0 = (p & 1) ? r01 : v0;
      float w1 = (p & 1) ? v1  : r01;
      float w2 = (p & 1) ? r23 : v2;
      float w3 = (p & 1) ? v3  : r23;
      float s02 = (p & 2) ? w0 : w2; float r02 = __shfl_xor(s02, 2);
      float s13 = (p & 2) ? w1 : w3; float r13 = __shfl_xor(s13, 2);
      float g0 = (p & 2) ? r02 : w0;   // i
      float g2 = (p & 2) ? w2  : r02;  // g
      float g1 = (p & 2) ? r13 : w1;   // f
      float g3 = (p & 2) ? w3  : r13;  // o
      float ig = sigmoidf_(g0), fg = sigmoidf_(g1);
      float gg = tanhf_(g2),   og = sigmoidf_(g3);
      float cv = fg*creg[cf] + ig*gg;
      creg[cf] = cv;
      float hv = og*tanhf_(cv);
      hac[cf] += hv;
      int hh = wv*32 + cf*4 + hhq;
      *(bf16*)swz256((char*)hb, nd2, hh*2) = (bf16)hv;
    }
    __syncthreads();
  }
  {
    int nn = tid >> 4, kb = tid & 15;
    i32x4 v = *(const i32x4*)swz256((char*)hb, nn, kb*16);
    *(i32x4*)(hsG + nn*128 + kb*8) = v;
  }
  float* hm = hsum + ((size_t)dir*2048 + n0)*128;
  #pragma unroll
  for (int cf = 0; cf < 8; ++cf) {
    int hh = wv*32 + cf*4 + hhq;
    size_t idx = (size_t)nd2*128 + hh;
    cG[idx] = creg[cf];
    hm[idx] += hac[cf];
  }
}

// ---------------- feats = mean over T of [hf, hr] ----------------
__global__ __launch_bounds__(256) void feats_kernel(const float* __restrict__ hsum, float* __restrict__ feats)
{
  int idx = blockIdx.x*256 + threadIdx.x;
  int k = idx & 255, n = idx >> 8;
  float v = (k < 128) ? hsum[(size_t)n*128 + k]
                      : hsum[(size_t)2048*128 + (size_t)n*128 + (k - 128)];
  feats[idx] = v * 0.0078125f;
}

// ---------------- Wh = in @ W^T  ([2048,K] x [128,K]) ----------------
template<int K>
__global__ __launch_bounds__(256) void node_gemm_kernel(
    const float* __restrict__ inp, const float* __restrict__ W, float* __restrict__ outp)
{
  __shared__ float ft[32][K];
  const int i0 = blockIdx.x*32, tid = threadIdx.x;
  for (int i = tid; i < 32*K; i += 256) ft[i/K][i%K] = inp[(size_t)i0*K + i];
  __syncthreads();
  const int f = tid & 127, ih = (tid >> 7)*16;
  float acc[16];
  #pragma unroll
  for (int ii = 0; ii < 16; ++ii) acc[ii] = 0.f;
  const float* wp = W + (size_t)f*K;
  for (int k = 0; k < K; k += 4) {
    const float4 wv = *reinterpret_cast<const float4*>(&wp[k]);
    #pragma unroll
    for (int ii = 0; ii < 16; ++ii) {
      const float* fp = &ft[ih+ii][k];
      acc[ii] += fp[0]*wv.x + fp[1]*wv.y + fp[2]*wv.z + fp[3]*wv.w;
    }
  }
  #pragma unroll
  for (int ii = 0; ii < 16; ++ii) outp[(size_t)(i0+ih+ii)*128 + f] = acc[ii];
}

// ---------------- s1/s2 per node ----------------
__global__ __launch_bounds__(256) void gat_s_kernel(const float* __restrict__ Wh,
    const float* __restrict__ a, float* __restrict__ s1, float* __restrict__ s2)
{
  const int node = blockIdx.x*4 + (threadIdx.x >> 6);
  const int l = threadIdx.x & 63;
  const float w0 = Wh[(size_t)node*128 + l], w1 = Wh[(size_t)node*128 + 64 + l];
  float v1 = w0*a[l]     + w1*a[64+l];
  float v2 = w0*a[128+l] + w1*a[192+l];
  #pragma unroll
  for (int off = 32; off > 0; off >>= 1) { v1 += __shfl_down(v1, off); v2 += __shfl_down(v2, off); }
  if (l == 0) { s1[node] = v1; s2[node] = v2; }
}

// ---------------- GAT attention row ----------------
__global__ __launch_bounds__(256) void gat_attn_kernel(const float* __restrict__ Wh,
    const float* __restrict__ s1, const float* __restrict__ s2v,
    const int* __restrict__ adj, float* __restrict__ outp, int applyElu)
{
  __shared__ float ebuf[2048];
  __shared__ float red[256];
  const int i = blockIdx.x, tid = threadIdx.x;
  const float s1i = s1[i];
  const int* arow = adj + (size_t)i*2048;
  float ev[8]; float lmax = -3.0e38f;
  #pragma unroll
  for (int r = 0; r < 8; ++r) {
    int j = tid + r*256;
    float e = s1i + s2v[j];
    e = (e > 0.f) ? e : 0.2f*e;
    e = (arow[j] > 0) ? e : -3.0e38f;
    ev[r] = e; lmax = fmaxf(lmax, e);
  }
  red[tid] = lmax; __syncthreads();
  for (int off = 128; off > 0; off >>= 1) { if (tid < off) red[tid] = fmaxf(red[tid], red[tid+off]); __syncthreads(); }
  const float m = red[0]; __syncthreads();
  float lsum = 0.f;
  #pragma unroll
  for (int r = 0; r < 8; ++r) { float pp = __expf(ev[r] - m); ebuf[tid + r*256] = pp; lsum += pp; }
  red[tid] = lsum; __syncthreads();
  for (int off = 128; off > 0; off >>= 1) { if (tid < off) red[tid] += red[tid+off]; __syncthreads(); }
  const float inv = 1.0f/red[0];
  __syncthreads();
  const int f = tid & 127, jh = tid >> 7;
  float acc = 0.f;
  for (int j = 0; j < 1024; ++j) acc += ebuf[jh*1024 + j] * Wh[(size_t)(jh*1024 + j)*128 + f];
  red[tid] = acc; __syncthreads();
  if (tid < 128) {
    float v = (red[tid] + red[tid+128])*inv;
    if (applyElu) v = (v > 0.f) ? v : (__expf(v) - 1.0f);
    outp[(size_t)i*128 + tid] = v;
  }
}

// ---------------- launch ----------------
extern "C" void kernel_launch(void* const* d_in, const int* in_sizes, int n_in,
                              void* d_out, int out_size, void* d_ws, size_t ws_size,
                              hipStream_t stream)
{
  (void)in_sizes; (void)n_in; (void)out_size; (void)ws_size;
  const float* x    = (const float*)d_in[0];
  const int*   adj  = (const int*)d_in[1];
  const float* c1w  = (const float*)d_in[2];
  const float* c1b  = (const float*)d_in[3];
  const float* bn1g = (const float*)d_in[4];
  const float* bn1b = (const float*)d_in[5];
  const float* c2w  = (const float*)d_in[6];
  const float* c2b  = (const float*)d_in[7];
  const float* bn2g = (const float*)d_in[8];
  const float* bn2b = (const float*)d_in[9];
  const float* wif  = (const float*)d_in[10];
  const float* whf  = (const float*)d_in[11];
  const float* bfv  = (const float*)d_in[12];
  const float* wir  = (const float*)d_in[13];
  const float* whr  = (const float*)d_in[14];
  const float* brv  = (const float*)d_in[15];
  const float* g1W  = (const float*)d_in[16];
  const float* g1a  = (const float*)d_in[17];
  const float* g2W  = (const float*)d_in[18];
  const float* g2a  = (const float*)d_in[19];
  float* outp = (float*)d_out;
  float* ws   = (float*)d_ws;

  bf16* y12    = (bf16*)(ws + OFF_A);      // y1 then y2
  bf16* pool1t = (bf16*)(ws + OFF_B);      // [2048][256][64]
  bf16* pool2t = (bf16*)(ws + OFF_B1);     // [2048][128][128]
  bf16* preB   = (bf16*)(ws + OFF_B);      // [2][16][512][2048] (after pool1t dead)
  bf16* whh_g  = (bf16*)(ws + OFF_WHHG);
  bf16* wih_g  = (bf16*)(ws + OFF_WIHG);
  float* bias_g= ws + OFF_BIAS;
  bf16* hst    = (bf16*)(ws + OFF_H);
  float* cstG  = ws + OFF_C;
  float* hsm   = ws + OFF_HSUM;
  float* feats = ws + OFF_FEAT;
  float* Wh1   = ws + OFF_WH1;
  float* s1a   = ws + OFF_S1A;
  float* s2a   = ws + OFF_S2A;
  float* h1    = ws + OFF_H1;
  float* Wh2   = ws + OFF_WH2;
  float* s1b   = ws + OFF_S1B;
  float* s2b   = ws + OFF_S2B;
  float* stat  = ws + OFF_STAT;

  // zero h, c, hsum (contiguous) + BN stat accumulators
  hipMemsetAsync(ws + OFF_H, 0, (size_t)(262144 + 524288 + 524288)*sizeof(float), stream);
  hipMemsetAsync(stat, 0, 512*sizeof(float), stream);

  prep_kernel<<<dim3(256,2),256,0,stream>>>(whf, whr, wif, wir, bfv, brv, whh_g, wih_g, bias_g);

  // conv1 -> BN -> relu -> pool (+transpose)
  conv1_kernel<<<dim3(2,2048),512,0,stream>>>(x, c1w, c1b, y12);
  bn_stats_kernel<<<dim3(64,32),256,0,stream>>>(y12, stat, 64, 512);
  bn_finalize_kernel<<<1,128,0,stream>>>(stat, bn1g, bn1b, 64, 1.0f/(2048.0f*512.0f));
  poolT_kernel<64,256><<<2048,256,0,stream>>>(y12, stat, pool1t);

  // conv2 -> BN -> relu -> pool (+transpose)
  hipMemsetAsync(stat, 0, 256*sizeof(float), stream);
  conv2_kernel<<<2048,512,0,stream>>>(pool1t, c2w, c2b, y12);
  bn_stats_kernel<<<dim3(128,32),256,0,stream>>>(y12, stat, 128, 256);
  bn_finalize_kernel<<<1,128,0,stream>>>(stat, bn2g, bn2b, 128, 1.0f/(2048.0f*256.0f));
  poolT_kernel<128,128><<<2048,256,0,stream>>>(y12, stat, pool2t);

  // biLSTM: 8 chunks of 16 timesteps
  for (int ch = 0; ch < 8; ++ch) {
    inproj_kernel<<<dim3(16,4,32),256,0,stream>>>(pool2t, wih_g, bias_g, preB, ch);
    lstm_kernel<<<dim3(128,2),256,0,stream>>>(preB, whh_g, hst, cstG, hsm);
  }
  feats_kernel<<<2048,256,0,stream>>>(hsm, feats);

  // GAT x2
  node_gemm_kernel<256><<<64,256,0,stream>>>(feats, g1W, Wh1);
  gat_s_kernel<<<512,256,0,stream>>>(Wh1, g1a, s1a, s2a);
  gat_attn_kernel<<<2048,256,0,stream>>>(Wh1, s1a, s2a, adj, h1, 1);
  node_gemm_kernel<128><<<64,256,0,stream>>>(h1, g2W, Wh2);
  gat_s_kernel<<<512,256,0,stream>>>(Wh2, g2a, s1b, s2b);
  gat_attn_kernel<<<2048,256,0,stream>>>(Wh2, s1b, s2b, adj, outp, 0);
}

// Round 4
// 883.987 us; speedup vs baseline: 4.7387x; 1.8279x over previous
//
#include <hip/hip_runtime.h>

typedef unsigned int uint;
#define DI __device__ __forceinline__

typedef __bf16 bf16;
typedef __attribute__((ext_vector_type(4))) float f32x4;
typedef __attribute__((ext_vector_type(8))) __bf16 bf16x8;
typedef __attribute__((ext_vector_type(4))) int i32x4;

// ---------------- ws layout (float units) ----------------
constexpr size_t OFF_A    = 0;                    // 33,554,432 f: y1/y2 bf16 [N][C][T]
constexpr size_t OFF_B    = 33554432;             // pool1t bf16
constexpr size_t OFF_B1   = OFF_B + 16777216;     // pool2t bf16 [2048][128][128]
constexpr size_t OFF_WHHG = 67108864;             // bf16 [2][512][128]  (65,536 f)
constexpr size_t OFF_WIHG = OFF_WHHG + 65536;     // bf16 [2][512][128]  (65,536 f)
constexpr size_t OFF_BIAS = OFF_WIHG + 65536;     // f32 [2][512]        (1,024 f)
constexpr size_t OFF_HSUM = OFF_BIAS + 1024;      // f32 [2][2048][128]
constexpr size_t OFF_FEAT = OFF_HSUM + 524288;    // f32 [2048][256]
constexpr size_t OFF_WH1  = OFF_FEAT + 524288;    // f32 [2048][128]
constexpr size_t OFF_S1A  = OFF_WH1 + 262144;
constexpr size_t OFF_S2A  = OFF_S1A + 2048;
constexpr size_t OFF_H1   = OFF_S2A + 2048;
constexpr size_t OFF_WH2  = OFF_H1 + 262144;
constexpr size_t OFF_S1B  = OFF_WH2 + 262144;
constexpr size_t OFF_S2B  = OFF_S1B + 2048;
constexpr size_t OFF_STAT = OFF_S2B + 2048;       // sum[128] sumsq[128] scale[128] shift[128]

DI float bflo(uint u){ union { uint i; float f; } v; v.i = u << 16;         return v.f; }
DI float bfhi(uint u){ union { uint i; float f; } v; v.i = u & 0xffff0000u; return v.f; }
DI float sigmoidf_(float x){ return 1.0f/(1.0f + __expf(-x)); }
DI float tanhf_(float x){ float e = __expf(-2.0f*fabsf(x)); float r = (1.0f-e)/(1.0f+e); return x>=0.0f ? r : -r; }

DI f32x4 mfma16(i32x4 a, i32x4 b, f32x4 c){
  return __builtin_amdgcn_mfma_f32_16x16x32_bf16(
      __builtin_bit_cast(bf16x8, a), __builtin_bit_cast(bf16x8, b), c, 0, 0, 0);
}

// swizzled LDS address helpers (rows of 128B / 256B, XOR bits[4:6] by row&7)
DI char* swz128(char* base, int row, int byteInRow){ return base + row*128 + (byteInRow ^ ((row&7)<<4)); }
DI char* swz256(char* base, int row, int byteInRow){ return base + row*256 + (byteInRow ^ ((row&7)<<4)); }

// ---------------- prep: gate-interleaved bf16 weights ----------------
// c = hh*4 + gate ; src row = gate*128 + hh
__global__ void prep_kernel(const float* __restrict__ whf, const float* __restrict__ whr,
                            const float* __restrict__ wif, const float* __restrict__ wir,
                            const float* __restrict__ bfv, const float* __restrict__ brv,
                            bf16* __restrict__ whh_g, bf16* __restrict__ wih_g,
                            float* __restrict__ bias_g)
{
  const int dir = blockIdx.y;
  const float* whh = dir ? whr : whf;
  const float* wih = dir ? wir : wif;
  const float* bb  = dir ? brv : bfv;
  int idx = blockIdx.x*256 + threadIdx.x;        // < 65536
  int c = idx >> 7, d = idx & 127;
  int src = ((c & 3)*128 + (c >> 2))*128 + d;
  whh_g[(size_t)dir*65536 + idx] = (bf16)whh[src];
  wih_g[(size_t)dir*65536 + idx] = (bf16)wih[src];
  if (idx < 512) bias_g[dir*512 + idx] = bb[(idx & 3)*128 + (idx >> 2)];
}

// ---------------- conv1: x f32 [2048][64][512] -> y1 bf16 [2048][64][512] ----------------
__global__ __launch_bounds__(512) void conv1_kernel(
    const float* __restrict__ x, const float* __restrict__ w,
    const float* __restrict__ bias, bf16* __restrict__ y)
{
  __shared__ bf16 xa[258*64];     // [row=t-t0+1][ci], 128B rows, swizzled
  __shared__ bf16 wb[3*64*64];    // [dk*64+co][ci], swizzled
  const int n = blockIdx.y, t0 = blockIdx.x*256, tid = threadIdx.x;
  for (int i = tid; i < 12288; i += 512) {
    int ci = i & 63, co = (i >> 6) & 63, dk = i >> 12;
    int row = dk*64 + co;
    *(bf16*)swz128((char*)wb, row, ci*2) = (bf16)w[(co*64 + ci)*3 + dk];
  }
  for (int i = tid; i < 16384; i += 512) {
    int tt = i & 255, ci = i >> 8;
    int row = tt + 1;
    *(bf16*)swz128((char*)xa, row, ci*2) = (bf16)x[((size_t)n*64 + ci)*512 + t0 + tt];
  }
  if (tid < 128) {
    int ci = tid >> 1, e = tid & 1;
    int row = e ? 257 : 0;
    int t = t0 + (e ? 256 : -1);
    float v = (t >= 0 && t < 512) ? x[((size_t)n*64 + ci)*512 + t] : 0.0f;
    *(bf16*)swz128((char*)xa, row, ci*2) = (bf16)v;
  }
  __syncthreads();
  const int lane = tid & 63, wv = tid >> 6;
  const int m0 = (wv & 3)*64, c0 = (wv >> 2)*32;
  const int l15 = lane & 15, lh = lane >> 4;
  f32x4 acc[4][2];
  #pragma unroll
  for (int mf = 0; mf < 4; ++mf)
    #pragma unroll
    for (int cf = 0; cf < 2; ++cf) {
      float bb = bias[c0 + cf*16 + l15];
      acc[mf][cf] = (f32x4){bb, bb, bb, bb};
    }
  #pragma unroll
  for (int dk = 0; dk < 3; ++dk)
    #pragma unroll
    for (int ks = 0; ks < 2; ++ks) {
      const int kb = ks*64 + lh*16;
      i32x4 bfr[2], afr[4];
      #pragma unroll
      for (int cf = 0; cf < 2; ++cf) {
        int row = dk*64 + c0 + cf*16 + l15;
        bfr[cf] = *(const i32x4*)swz128((char*)wb, row, kb);
      }
      #pragma unroll
      for (int mf = 0; mf < 4; ++mf) {
        int row = m0 + mf*16 + l15 + dk;
        afr[mf] = *(const i32x4*)swz128((char*)xa, row, kb);
      }
      #pragma unroll
      for (int mf = 0; mf < 4; ++mf)
        #pragma unroll
        for (int cf = 0; cf < 2; ++cf)
          acc[mf][cf] = mfma16(afr[mf], bfr[cf], acc[mf][cf]);
    }
  #pragma unroll
  for (int mf = 0; mf < 4; ++mf)
    #pragma unroll
    for (int cf = 0; cf < 2; ++cf) {
      int co = c0 + cf*16 + l15;
      int tt = t0 + m0 + mf*16 + lh*4;
      union { bf16 h[4]; uint2 u; } pk;
      #pragma unroll
      for (int r = 0; r < 4; ++r) pk.h[r] = (bf16)acc[mf][cf][r];
      *(uint2*)&y[((size_t)n*64 + co)*512 + tt] = pk.u;
    }
}

// ---------------- conv2: pool1T bf16 [2048][256][64] -> y2 bf16 [2048][128][256] ----------------
__global__ __launch_bounds__(512) void conv2_kernel(
    const bf16* __restrict__ xin, const float* __restrict__ w,
    const float* __restrict__ bias, bf16* __restrict__ y)
{
  __shared__ bf16 xa[258*64];
  __shared__ bf16 wb[3*128*64];
  const int n = blockIdx.x, tid = threadIdx.x;
  for (int i = tid; i < 24576; i += 512) {
    int ci = i & 63, co = (i >> 6) & 127, dk = i >> 13;
    int row = dk*128 + co;
    *(bf16*)swz128((char*)wb, row, ci*2) = (bf16)w[(co*64 + ci)*3 + dk];
  }
  {
    const i32x4* src = (const i32x4*)(xin + (size_t)n*256*64);
    for (int i = tid; i < 2048; i += 512) {
      int row = (i >> 3) + 1, blk = i & 7;
      *(i32x4*)swz128((char*)xa, row, blk*16) = src[i];
    }
  }
  if (tid < 128) {
    int ci = tid >> 1, e = tid & 1;
    int row = e ? 257 : 0;
    *(bf16*)swz128((char*)xa, row, ci*2) = (bf16)0.0f;
  }
  __syncthreads();
  const int lane = tid & 63, wv = tid >> 6;
  const int m0 = (wv & 3)*64, c0 = (wv >> 2)*64;
  const int l15 = lane & 15, lh = lane >> 4;
  f32x4 acc[4][4];
  #pragma unroll
  for (int mf = 0; mf < 4; ++mf)
    #pragma unroll
    for (int cf = 0; cf < 4; ++cf) {
      float bb = bias[c0 + cf*16 + l15];
      acc[mf][cf] = (f32x4){bb, bb, bb, bb};
    }
  #pragma unroll
  for (int dk = 0; dk < 3; ++dk)
    #pragma unroll
    for (int ks = 0; ks < 2; ++ks) {
      const int kb = ks*64 + lh*16;
      i32x4 bfr[4], afr[4];
      #pragma unroll
      for (int cf = 0; cf < 4; ++cf) {
        int row = dk*128 + c0 + cf*16 + l15;
        bfr[cf] = *(const i32x4*)swz128((char*)wb, row, kb);
      }
      #pragma unroll
      for (int mf = 0; mf < 4; ++mf) {
        int row = m0 + mf*16 + l15 + dk;
        afr[mf] = *(const i32x4*)swz128((char*)xa, row, kb);
      }
      #pragma unroll
      for (int mf = 0; mf < 4; ++mf)
        #pragma unroll
        for (int cf = 0; cf < 4; ++cf)
          acc[mf][cf] = mfma16(afr[mf], bfr[cf], acc[mf][cf]);
    }
  #pragma unroll
  for (int mf = 0; mf < 4; ++mf)
    #pragma unroll
    for (int cf = 0; cf < 4; ++cf) {
      int co = c0 + cf*16 + l15;
      int tt = m0 + mf*16 + lh*4;
      union { bf16 h[4]; uint2 u; } pk;
      #pragma unroll
      for (int r = 0; r < 4; ++r) pk.h[r] = (bf16)acc[mf][cf][r];
      *(uint2*)&y[((size_t)n*128 + co)*256 + tt] = pk.u;
    }
}

// ---------------- BN stats (training mode, over N,T per channel) ----------------
__global__ __launch_bounds__(256) void bn_stats_kernel(
    const bf16* __restrict__ y, float* __restrict__ stat, int C, int T)
{
  const int c = blockIdx.x, n0 = blockIdx.y*64, tid = threadIdx.x;
  float s = 0.f, q = 0.f;
  const int per = T/256;
  for (int n = n0; n < n0 + 64; ++n) {
    const bf16* p = &y[(size_t)(n*C + c)*T];
    for (int r = 0; r < per; ++r) { float v = (float)p[tid + r*256]; s += v; q += v*v; }
  }
  __shared__ float rs[256], rq[256];
  rs[tid] = s; rq[tid] = q; __syncthreads();
  for (int off = 128; off > 0; off >>= 1) {
    if (tid < off) { rs[tid] += rs[tid+off]; rq[tid] += rq[tid+off]; }
    __syncthreads();
  }
  if (tid == 0) { atomicAdd(&stat[c], rs[0]); atomicAdd(&stat[128+c], rq[0]); }
}

__global__ void bn_finalize_kernel(float* __restrict__ stat, const float* __restrict__ g,
                                   const float* __restrict__ b, int C, float invCnt)
{
  int c = threadIdx.x;
  if (c < C) {
    float m  = stat[c]*invCnt;
    float v  = stat[128+c]*invCnt - m*m;
    float sc = g[c]*rsqrtf(v + 1e-5f);
    stat[256+c] = sc;
    stat[384+c] = b[c] - m*sc;
  }
}

// ---------------- BN apply + ReLU + maxpool2 + transpose: [n][C][2*TH] -> bf16 [n][TH][C] ----------------
template<int C, int TH>
__global__ __launch_bounds__(256) void poolT_kernel(
    const bf16* __restrict__ yin, const float* __restrict__ stat, bf16* __restrict__ outp)
{
  __shared__ bf16 buf[C][TH + 2];
  const int n = blockIdx.x, tid = threadIdx.x;
  const uint* src = (const uint*)(yin + (size_t)n*C*TH*2);
  for (int i = tid; i < C*TH; i += 256) {
    int th = i & (TH - 1), c = i / TH;
    uint u = src[i];
    float sc = stat[256 + c], sh = stat[384 + c];
    float a = fmaxf(sc*bflo(u) + sh, 0.f);
    float b = fmaxf(sc*bfhi(u) + sh, 0.f);
    buf[c][th] = (bf16)fmaxf(a, b);
  }
  __syncthreads();
  bf16* dst = outp + (size_t)n*TH*C;
  for (int i = tid; i < TH*C/2; i += 256) {
    int cp = i & (C/2 - 1), th = i / (C/2);
    union { bf16 h[2]; uint u; } pk;
    pk.h[0] = buf[2*cp][th]; pk.h[1] = buf[2*cp + 1][th];
    *(uint*)&dst[th*C + 2*cp] = pk.u;
  }
}

// ---------------- fused biLSTM: one persistent kernel, weights in registers ----------------
// grid 256 = (128 node-groups x 2 dirs), block 512 = 8 waves; wave wv owns gate-cols
// [wv*64, wv*64+64). wih+whh bf16 fragments in VGPRs; h bf16 in 4KB swizzled LDS; c in regs.
// Per t: 16 MFMA inproj (x frags direct from global, prefetched 1 iter ahead) + 16 MFMA
// recurrence + quad-butterfly nonlinearity. 2 barriers/t.
__global__ __launch_bounds__(512, 2) void lstm_fused_kernel(
    const bf16* __restrict__ p2t, const bf16* __restrict__ wih_g,
    const bf16* __restrict__ whh_g, const float* __restrict__ bias_g,
    float* __restrict__ hsum)
{
  __shared__ bf16 hb[2048];   // [16 n][128 hh], 256B rows, swizzled
  const int z = blockIdx.x;
  const int dir = z & 1, n0 = (z >> 1)*16;
  const int tid = threadIdx.x, lane = tid & 63, wv = tid >> 6;
  const int l15 = lane & 15, lh = lane >> 4;
  i32x4 wihr[4][4], whhr[4][4];
  {
    const bf16* wi = wih_g + (size_t)dir*65536;
    const bf16* wh = whh_g + (size_t)dir*65536;
    #pragma unroll
    for (int cf = 0; cf < 4; ++cf) {
      int c = wv*64 + cf*16 + l15;
      #pragma unroll
      for (int ks = 0; ks < 4; ++ks) {
        wihr[cf][ks] = *(const i32x4*)(wi + (size_t)c*128 + ks*32 + lh*8);
        whhr[cf][ks] = *(const i32x4*)(wh + (size_t)c*128 + ks*32 + lh*8);
      }
    }
  }
  float bias0[4];
  #pragma unroll
  for (int cf = 0; cf < 4; ++cf) bias0[cf] = bias_g[dir*512 + wv*64 + cf*16 + l15];
  for (int i = tid; i < 256; i += 512) ((i32x4*)hb)[i] = (i32x4){0,0,0,0};
  const int p = lane & 3, hhq = (lane >> 2) & 3;
  const int nd2 = lh*4 + p;
  float creg[4] = {0.f,0.f,0.f,0.f}, hac[4] = {0.f,0.f,0.f,0.f};
  const bf16* xrow = p2t + ((size_t)(n0 + l15)*128)*128;
  i32x4 xf[4];
  {
    int ts0 = dir ? 127 : 0;
    #pragma unroll
    for (int ks = 0; ks < 4; ++ks)
      xf[ks] = *(const i32x4*)(xrow + (size_t)ts0*128 + ks*32 + lh*8);
  }
  __syncthreads();
  for (int t = 0; t < 128; ++t) {
    i32x4 xn[4];
    {
      int tn = (t + 1 < 128) ? t + 1 : 127;
      int tsn = dir ? 127 - tn : tn;
      #pragma unroll
      for (int ks = 0; ks < 4; ++ks)
        xn[ks] = *(const i32x4*)(xrow + (size_t)tsn*128 + ks*32 + lh*8);
    }
    f32x4 acc[4];
    #pragma unroll
    for (int cf = 0; cf < 4; ++cf) acc[cf] = (f32x4){bias0[cf], bias0[cf], bias0[cf], bias0[cf]};
    #pragma unroll
    for (int cf = 0; cf < 4; ++cf)
      #pragma unroll
      for (int ks = 0; ks < 4; ++ks)
        acc[cf] = mfma16(xf[ks], wihr[cf][ks], acc[cf]);
    i32x4 af[4];
    #pragma unroll
    for (int ks = 0; ks < 4; ++ks)
      af[ks] = *(const i32x4*)swz256((char*)hb, l15, ks*64 + lh*16);
    #pragma unroll
    for (int cf = 0; cf < 4; ++cf)
      #pragma unroll
      for (int ks = 0; ks < 4; ++ks)
        acc[cf] = mfma16(af[ks], whhr[cf][ks], acc[cf]);
    __syncthreads();   // all waves done reading h(t-1) (drain before barrier)
    #pragma unroll
    for (int cf = 0; cf < 4; ++cf) {
      float v0 = acc[cf][0], v1 = acc[cf][1], v2 = acc[cf][2], v3 = acc[cf][3];
      float s01 = (p & 1) ? v0 : v1; float r01 = __shfl_xor(s01, 1);
      float s23 = (p & 1) ? v2 : v3; float r23 = __shfl_xor(s23, 1);
      float w0 = (p & 1) ? r01 : v0;
      float w1 = (p & 1) ? v1  : r01;
      float w2 = (p & 1) ? r23 : v2;
      float w3 = (p & 1) ? v3  : r23;
      float s02 = (p & 2) ? w0 : w2; float r02 = __shfl_xor(s02, 2);
      float s13 = (p & 2) ? w1 : w3; float r13 = __shfl_xor(s13, 2);
      float g0 = (p & 2) ? r02 : w0;   // i
      float g2 = (p & 2) ? w2  : r02;  // g
      float g1 = (p & 2) ? r13 : w1;   // f
      float g3 = (p & 2) ? w3  : r13;  // o
      float ig = sigmoidf_(g0), fg = sigmoidf_(g1);
      float gg = tanhf_(g2),   og = sigmoidf_(g3);
      float cv = fg*creg[cf] + ig*gg;
      creg[cf] = cv;
      float hv = og*tanhf_(cv);
      hac[cf] += hv;
      int hh = wv*16 + cf*4 + hhq;
      *(bf16*)swz256((char*)hb, nd2, hh*2) = (bf16)hv;
    }
    __syncthreads();   // h(t) visible
    #pragma unroll
    for (int ks = 0; ks < 4; ++ks) xf[ks] = xn[ks];
  }
  float* hm = hsum + ((size_t)dir*2048 + n0)*128;
  #pragma unroll
  for (int cf = 0; cf < 4; ++cf) {
    int hh = wv*16 + cf*4 + hhq;
    hm[(size_t)nd2*128 + hh] = hac[cf];
  }
}

// ---------------- feats = mean over T of [hf, hr] ----------------
__global__ __launch_bounds__(256) void feats_kernel(const float* __restrict__ hsum, float* __restrict__ feats)
{
  int idx = blockIdx.x*256 + threadIdx.x;
  int k = idx & 255, n = idx >> 8;
  float v = (k < 128) ? hsum[(size_t)n*128 + k]
                      : hsum[(size_t)2048*128 + (size_t)n*128 + (k - 128)];
  feats[idx] = v * 0.0078125f;
}

// ---------------- Wh = in @ W^T  ([2048,K] x [128,K]) ----------------
template<int K>
__global__ __launch_bounds__(256) void node_gemm_kernel(
    const float* __restrict__ inp, const float* __restrict__ W, float* __restrict__ outp)
{
  __shared__ float ft[32][K];
  const int i0 = blockIdx.x*32, tid = threadIdx.x;
  for (int i = tid; i < 32*K; i += 256) ft[i/K][i%K] = inp[(size_t)i0*K + i];
  __syncthreads();
  const int f = tid & 127, ih = (tid >> 7)*16;
  float acc[16];
  #pragma unroll
  for (int ii = 0; ii < 16; ++ii) acc[ii] = 0.f;
  const float* wp = W + (size_t)f*K;
  for (int k = 0; k < K; k += 4) {
    const float4 wv = *reinterpret_cast<const float4*>(&wp[k]);
    #pragma unroll
    for (int ii = 0; ii < 16; ++ii) {
      const float* fp = &ft[ih+ii][k];
      acc[ii] += fp[0]*wv.x + fp[1]*wv.y + fp[2]*wv.z + fp[3]*wv.w;
    }
  }
  #pragma unroll
  for (int ii = 0; ii < 16; ++ii) outp[(size_t)(i0+ih+ii)*128 + f] = acc[ii];
}

// ---------------- s1/s2 per node ----------------
__global__ __launch_bounds__(256) void gat_s_kernel(const float* __restrict__ Wh,
    const float* __restrict__ a, float* __restrict__ s1, float* __restrict__ s2)
{
  const int node = blockIdx.x*4 + (threadIdx.x >> 6);
  const int l = threadIdx.x & 63;
  const float w0 = Wh[(size_t)node*128 + l], w1 = Wh[(size_t)node*128 + 64 + l];
  float v1 = w0*a[l]     + w1*a[64+l];
  float v2 = w0*a[128+l] + w1*a[192+l];
  #pragma unroll
  for (int off = 32; off > 0; off >>= 1) { v1 += __shfl_down(v1, off); v2 += __shfl_down(v2, off); }
  if (l == 0) { s1[node] = v1; s2[node] = v2; }
}

// ---------------- GAT attention row ----------------
__global__ __launch_bounds__(256) void gat_attn_kernel(const float* __restrict__ Wh,
    const float* __restrict__ s1, const float* __restrict__ s2v,
    const int* __restrict__ adj, float* __restrict__ outp, int applyElu)
{
  __shared__ float ebuf[2048];
  __shared__ float red[256];
  const int i = blockIdx.x, tid = threadIdx.x;
  const float s1i = s1[i];
  const int* arow = adj + (size_t)i*2048;
  float ev[8]; float lmax = -3.0e38f;
  #pragma unroll
  for (int r = 0; r < 8; ++r) {
    int j = tid + r*256;
    float e = s1i + s2v[j];
    e = (e > 0.f) ? e : 0.2f*e;
    e = (arow[j] > 0) ? e : -3.0e38f;
    ev[r] = e; lmax = fmaxf(lmax, e);
  }
  red[tid] = lmax; __syncthreads();
  for (int off = 128; off > 0; off >>= 1) { if (tid < off) red[tid] = fmaxf(red[tid], red[tid+off]); __syncthreads(); }
  const float m = red[0]; __syncthreads();
  float lsum = 0.f;
  #pragma unroll
  for (int r = 0; r < 8; ++r) { float pp = __expf(ev[r] - m); ebuf[tid + r*256] = pp; lsum += pp; }
  red[tid] = lsum; __syncthreads();
  for (int off = 128; off > 0; off >>= 1) { if (tid < off) red[tid] += red[tid+off]; __syncthreads(); }
  const float inv = 1.0f/red[0];
  __syncthreads();
  const int f = tid & 127, jh = tid >> 7;
  float acc = 0.f;
  for (int j = 0; j < 1024; ++j) acc += ebuf[jh*1024 + j] * Wh[(size_t)(jh*1024 + j)*128 + f];
  red[tid] = acc; __syncthreads();
  if (tid < 128) {
    float v = (red[tid] + red[tid+128])*inv;
    if (applyElu) v = (v > 0.f) ? v : (__expf(v) - 1.0f);
    outp[(size_t)i*128 + tid] = v;
  }
}

// ---------------- launch ----------------
extern "C" void kernel_launch(void* const* d_in, const int* in_sizes, int n_in,
                              void* d_out, int out_size, void* d_ws, size_t ws_size,
                              hipStream_t stream)
{
  (void)in_sizes; (void)n_in; (void)out_size; (void)ws_size;
  const float* x    = (const float*)d_in[0];
  const int*   adj  = (const int*)d_in[1];
  const float* c1w  = (const float*)d_in[2];
  const float* c1b  = (const float*)d_in[3];
  const float* bn1g = (const float*)d_in[4];
  const float* bn1b = (const float*)d_in[5];
  const float* c2w  = (const float*)d_in[6];
  const float* c2b  = (const float*)d_in[7];
  const float* bn2g = (const float*)d_in[8];
  const float* bn2b = (const float*)d_in[9];
  const float* wif  = (const float*)d_in[10];
  const float* whf  = (const float*)d_in[11];
  const float* bfv  = (const float*)d_in[12];
  const float* wir  = (const float*)d_in[13];
  const float* whr  = (const float*)d_in[14];
  const float* brv  = (const float*)d_in[15];
  const float* g1W  = (const float*)d_in[16];
  const float* g1a  = (const float*)d_in[17];
  const float* g2W  = (const float*)d_in[18];
  const float* g2a  = (const float*)d_in[19];
  float* outp = (float*)d_out;
  float* ws   = (float*)d_ws;

  bf16* y12    = (bf16*)(ws + OFF_A);
  bf16* pool1t = (bf16*)(ws + OFF_B);      // [2048][256][64]
  bf16* pool2t = (bf16*)(ws + OFF_B1);     // [2048][128][128]
  bf16* whh_g  = (bf16*)(ws + OFF_WHHG);
  bf16* wih_g  = (bf16*)(ws + OFF_WIHG);
  float* bias_g= ws + OFF_BIAS;
  float* hsm   = ws + OFF_HSUM;
  float* feats = ws + OFF_FEAT;
  float* Wh1   = ws + OFF_WH1;
  float* s1a   = ws + OFF_S1A;
  float* s2a   = ws + OFF_S2A;
  float* h1    = ws + OFF_H1;
  float* Wh2   = ws + OFF_WH2;
  float* s1b   = ws + OFF_S1B;
  float* s2b   = ws + OFF_S2B;
  float* stat  = ws + OFF_STAT;

  hipMemsetAsync(stat, 0, 512*sizeof(float), stream);

  prep_kernel<<<dim3(256,2),256,0,stream>>>(whf, whr, wif, wir, bfv, brv, whh_g, wih_g, bias_g);

  // conv1 -> BN -> relu -> pool (+transpose)
  conv1_kernel<<<dim3(2,2048),512,0,stream>>>(x, c1w, c1b, y12);
  bn_stats_kernel<<<dim3(64,32),256,0,stream>>>(y12, stat, 64, 512);
  bn_finalize_kernel<<<1,128,0,stream>>>(stat, bn1g, bn1b, 64, 1.0f/(2048.0f*512.0f));
  poolT_kernel<64,256><<<2048,256,0,stream>>>(y12, stat, pool1t);

  // conv2 -> BN -> relu -> pool (+transpose)
  hipMemsetAsync(stat, 0, 256*sizeof(float), stream);
  conv2_kernel<<<2048,512,0,stream>>>(pool1t, c2w, c2b, y12);
  bn_stats_kernel<<<dim3(128,32),256,0,stream>>>(y12, stat, 128, 256);
  bn_finalize_kernel<<<1,128,0,stream>>>(stat, bn2g, bn2b, 128, 1.0f/(2048.0f*256.0f));
  poolT_kernel<128,128><<<2048,256,0,stream>>>(y12, stat, pool2t);

  // fused biLSTM (single dispatch)
  lstm_fused_kernel<<<256,512,0,stream>>>(pool2t, wih_g, whh_g, bias_g, hsm);
  feats_kernel<<<2048,256,0,stream>>>(hsm, feats);

  // GAT x2
  node_gemm_kernel<256><<<64,256,0,stream>>>(feats, g1W, Wh1);
  gat_s_kernel<<<512,256,0,stream>>>(Wh1, g1a, s1a, s2a);
  gat_attn_kernel<<<2048,256,0,stream>>>(Wh1, s1a, s2a, adj, h1, 1);
  node_gemm_kernel<128><<<64,256,0,stream>>>(h1, g2W, Wh2);
  gat_s_kernel<<<512,256,0,stream>>>(Wh2, g2a, s1b, s2b);
  gat_attn_kernel<<<2048,256,0,stream>>>(Wh2, s1b, s2b, adj, outp, 0);
}

// Round 5
// 719.999 us; speedup vs baseline: 5.8180x; 1.2278x over previous
//
#include <hip/hip_runtime.h>

typedef unsigned int uint;
#define DI __device__ __forceinline__

typedef __bf16 bf16;
typedef __attribute__((ext_vector_type(4))) float f32x4;
typedef __attribute__((ext_vector_type(8))) __bf16 bf16x8;
typedef __attribute__((ext_vector_type(4))) int i32x4;

// ---------------- ws layout (float units) ----------------
constexpr size_t OFF_A    = 0;                    // y1/y2 bf16 [N][C][T]
constexpr size_t OFF_B    = 33554432;             // pool1t bf16
constexpr size_t OFF_B1   = OFF_B + 16777216;     // pool2t bf16 [2048][128][128]
constexpr size_t OFF_WHHG = 67108864;             // bf16 [2][512][128]
constexpr size_t OFF_WIHG = OFF_WHHG + 65536;     // bf16 [2][512][128]
constexpr size_t OFF_BIAS = OFF_WIHG + 65536;     // f32 [2][512]
constexpr size_t OFF_HSUM = OFF_BIAS + 1024;      // f32 [2][2048][128]
constexpr size_t OFF_FEAT = OFF_HSUM + 524288;    // f32 [2048][256]
constexpr size_t OFF_WH1  = OFF_FEAT + 524288;    // f32 [2048][128]
constexpr size_t OFF_S1A  = OFF_WH1 + 262144;
constexpr size_t OFF_S2A  = OFF_S1A + 2048;
constexpr size_t OFF_H1   = OFF_S2A + 2048;
constexpr size_t OFF_WH2  = OFF_H1 + 262144;
constexpr size_t OFF_S1B  = OFF_WH2 + 262144;
constexpr size_t OFF_S2B  = OFF_S1B + 2048;
constexpr size_t OFF_STAT = OFF_S2B + 2048;       // sum/sumsq/scale/shift
constexpr size_t OFF_W1P  = OFF_STAT + 512;       // bf16 12288 (pre-swizzled conv1 w)
constexpr size_t OFF_W2P  = OFF_W1P + 6144;       // bf16 24576 (pre-swizzled conv2 w)

DI float bflo(uint u){ union { uint i; float f; } v; v.i = u << 16;         return v.f; }
DI float bfhi(uint u){ union { uint i; float f; } v; v.i = u & 0xffff0000u; return v.f; }
DI float fexp2_(float x){ return __builtin_amdgcn_exp2f(x); }
DI float frcp_(float x){ return __builtin_amdgcn_rcpf(x); }
DI float sigf_(float x){ return frcp_(1.0f + fexp2_(x * -1.44269504f)); }
// tanh(x) = 1 - 2/(e^{2x}+1); saturates correctly at +/-inf
DI float tanhx_(float x){ return 1.0f - 2.0f*frcp_(1.0f + fexp2_(x * 2.88539009f)); }

DI f32x4 mfma16(i32x4 a, i32x4 b, f32x4 c){
  return __builtin_amdgcn_mfma_f32_16x16x32_bf16(
      __builtin_bit_cast(bf16x8, a), __builtin_bit_cast(bf16x8, b), c, 0, 0, 0);
}

// swizzled LDS address helpers (rows of 128B / 256B, XOR bits[4:6] by row&7)
DI char* swz128(char* base, int row, int byteInRow){ return base + row*128 + (byteInRow ^ ((row&7)<<4)); }
DI char* swz256(char* base, int row, int byteInRow){ return base + row*256 + (byteInRow ^ ((row&7)<<4)); }

// ---------------- prep: gate-interleaved LSTM weights + pre-swizzled conv weights ----------------
// lstm: c = hh*4 + gate ; src row = gate*128 + hh
__global__ void prep_kernel(const float* __restrict__ whf, const float* __restrict__ whr,
                            const float* __restrict__ wif, const float* __restrict__ wir,
                            const float* __restrict__ bfv, const float* __restrict__ brv,
                            const float* __restrict__ c1w, const float* __restrict__ c2w,
                            bf16* __restrict__ whh_g, bf16* __restrict__ wih_g,
                            float* __restrict__ bias_g,
                            bf16* __restrict__ w1p, bf16* __restrict__ w2p)
{
  const int dir = blockIdx.y;
  const float* whh = dir ? whr : whf;
  const float* wih = dir ? wir : wif;
  const float* bb  = dir ? brv : bfv;
  int idx = blockIdx.x*256 + threadIdx.x;        // < 65536
  int c = idx >> 7, d = idx & 127;
  int src = ((c & 3)*128 + (c >> 2))*128 + d;
  whh_g[(size_t)dir*65536 + idx] = (bf16)whh[src];
  wih_g[(size_t)dir*65536 + idx] = (bf16)wih[src];
  if (idx < 512) bias_g[dir*512 + idx] = bb[(idx & 3)*128 + (idx >> 2)];
  if (dir == 0) {
    if (idx < 12288) {
      int row = idx >> 6;
      int ci = (((idx & 63)*2) ^ ((row & 7) << 4)) >> 1;
      int co = row & 63, dk = row >> 6;
      w1p[idx] = (bf16)c1w[(co*64 + ci)*3 + dk];
    }
    if (idx < 24576) {
      int row = idx >> 6;
      int ci = (((idx & 63)*2) ^ ((row & 7) << 4)) >> 1;
      int co = row & 127, dk = row >> 7;
      w2p[idx] = (bf16)c2w[(co*64 + ci)*3 + dk];
    }
  }
}

// ---------------- conv1: x f32 [2048][64][512] -> y1 bf16 [2048][64][512] ----------------
__global__ __launch_bounds__(512) void conv1_kernel(
    const float* __restrict__ x, const bf16* __restrict__ w1p,
    const float* __restrict__ bias, bf16* __restrict__ y)
{
  __shared__ bf16 xa[258*64];     // [row=t-t0+1][ci], 128B rows, swizzled
  __shared__ bf16 wb[3*64*64];    // [dk*64+co][ci], swizzled (pre-swizzled copy)
  const int n = blockIdx.y, t0 = blockIdx.x*256, tid = threadIdx.x;
  {
    const i32x4* wsrc = (const i32x4*)w1p;
    for (int i = tid; i < 1536; i += 512) ((i32x4*)wb)[i] = wsrc[i];
  }
  for (int i = tid; i < 4096; i += 512) {
    int q = i & 63, ci = i >> 6;
    float4 v = *(const float4*)&x[((size_t)n*64 + ci)*512 + t0 + q*4];
    int row = q*4 + 1;
    *(bf16*)swz128((char*)xa, row+0, ci*2) = (bf16)v.x;
    *(bf16*)swz128((char*)xa, row+1, ci*2) = (bf16)v.y;
    *(bf16*)swz128((char*)xa, row+2, ci*2) = (bf16)v.z;
    *(bf16*)swz128((char*)xa, row+3, ci*2) = (bf16)v.w;
  }
  if (tid < 128) {
    int ci = tid >> 1, e = tid & 1;
    int row = e ? 257 : 0;
    int t = t0 + (e ? 256 : -1);
    float v = (t >= 0 && t < 512) ? x[((size_t)n*64 + ci)*512 + t] : 0.0f;
    *(bf16*)swz128((char*)xa, row, ci*2) = (bf16)v;
  }
  __syncthreads();
  const int lane = tid & 63, wv = tid >> 6;
  const int m0 = (wv & 3)*64, c0 = (wv >> 2)*32;
  const int l15 = lane & 15, lh = lane >> 4;
  f32x4 acc[4][2];
  #pragma unroll
  for (int mf = 0; mf < 4; ++mf)
    #pragma unroll
    for (int cf = 0; cf < 2; ++cf) {
      float bb = bias[c0 + cf*16 + l15];
      acc[mf][cf] = (f32x4){bb, bb, bb, bb};
    }
  #pragma unroll
  for (int dk = 0; dk < 3; ++dk)
    #pragma unroll
    for (int ks = 0; ks < 2; ++ks) {
      const int kb = ks*64 + lh*16;
      i32x4 bfr[2], afr[4];
      #pragma unroll
      for (int cf = 0; cf < 2; ++cf) {
        int row = dk*64 + c0 + cf*16 + l15;
        bfr[cf] = *(const i32x4*)swz128((char*)wb, row, kb);
      }
      #pragma unroll
      for (int mf = 0; mf < 4; ++mf) {
        int row = m0 + mf*16 + l15 + dk;
        afr[mf] = *(const i32x4*)swz128((char*)xa, row, kb);
      }
      #pragma unroll
      for (int mf = 0; mf < 4; ++mf)
        #pragma unroll
        for (int cf = 0; cf < 2; ++cf)
          acc[mf][cf] = mfma16(afr[mf], bfr[cf], acc[mf][cf]);
    }
  #pragma unroll
  for (int mf = 0; mf < 4; ++mf)
    #pragma unroll
    for (int cf = 0; cf < 2; ++cf) {
      int co = c0 + cf*16 + l15;
      int tt = t0 + m0 + mf*16 + lh*4;
      union { bf16 h[4]; uint2 u; } pk;
      #pragma unroll
      for (int r = 0; r < 4; ++r) pk.h[r] = (bf16)acc[mf][cf][r];
      *(uint2*)&y[((size_t)n*64 + co)*512 + tt] = pk.u;
    }
}

// ---------------- conv2: pool1T bf16 [2048][256][64] -> y2 bf16 [2048][128][256] ----------------
__global__ __launch_bounds__(512) void conv2_kernel(
    const bf16* __restrict__ xin, const bf16* __restrict__ w2p,
    const float* __restrict__ bias, bf16* __restrict__ y)
{
  __shared__ bf16 xa[258*64];
  __shared__ bf16 wb[3*128*64];
  const int n = blockIdx.x, tid = threadIdx.x;
  {
    const i32x4* wsrc = (const i32x4*)w2p;
    for (int i = tid; i < 3072; i += 512) ((i32x4*)wb)[i] = wsrc[i];
  }
  {
    const i32x4* src = (const i32x4*)(xin + (size_t)n*256*64);
    for (int i = tid; i < 2048; i += 512) {
      int row = (i >> 3) + 1, blk = i & 7;
      *(i32x4*)swz128((char*)xa, row, blk*16) = src[i];
    }
  }
  if (tid < 128) {
    int ci = tid >> 1, e = tid & 1;
    int row = e ? 257 : 0;
    *(bf16*)swz128((char*)xa, row, ci*2) = (bf16)0.0f;
  }
  __syncthreads();
  const int lane = tid & 63, wv = tid >> 6;
  const int m0 = (wv & 3)*64, c0 = (wv >> 2)*64;
  const int l15 = lane & 15, lh = lane >> 4;
  f32x4 acc[4][4];
  #pragma unroll
  for (int mf = 0; mf < 4; ++mf)
    #pragma unroll
    for (int cf = 0; cf < 4; ++cf) {
      float bb = bias[c0 + cf*16 + l15];
      acc[mf][cf] = (f32x4){bb, bb, bb, bb};
    }
  #pragma unroll
  for (int dk = 0; dk < 3; ++dk)
    #pragma unroll
    for (int ks = 0; ks < 2; ++ks) {
      const int kb = ks*64 + lh*16;
      i32x4 bfr[4], afr[4];
      #pragma unroll
      for (int cf = 0; cf < 4; ++cf) {
        int row = dk*128 + c0 + cf*16 + l15;
        bfr[cf] = *(const i32x4*)swz128((char*)wb, row, kb);
      }
      #pragma unroll
      for (int mf = 0; mf < 4; ++mf) {
        int row = m0 + mf*16 + l15 + dk;
        afr[mf] = *(const i32x4*)swz128((char*)xa, row, kb);
      }
      #pragma unroll
      for (int mf = 0; mf < 4; ++mf)
        #pragma unroll
        for (int cf = 0; cf < 4; ++cf)
          acc[mf][cf] = mfma16(afr[mf], bfr[cf], acc[mf][cf]);
    }
  #pragma unroll
  for (int mf = 0; mf < 4; ++mf)
    #pragma unroll
    for (int cf = 0; cf < 4; ++cf) {
      int co = c0 + cf*16 + l15;
      int tt = m0 + mf*16 + lh*4;
      union { bf16 h[4]; uint2 u; } pk;
      #pragma unroll
      for (int r = 0; r < 4; ++r) pk.h[r] = (bf16)acc[mf][cf][r];
      *(uint2*)&y[((size_t)n*128 + co)*256 + tt] = pk.u;
    }
}

// ---------------- BN stats (vectorized uint4 loads) ----------------
__global__ __launch_bounds__(256) void bn_stats_kernel(
    const bf16* __restrict__ y, float* __restrict__ stat, int C, int T)
{
  const int c = blockIdx.x, n0 = blockIdx.y*64, tid = threadIdx.x;
  float s = 0.f, q = 0.f;
  const int qpr = T >> 3;           // uint4 (8 bf16) per row
  for (int i = tid; i < 64*qpr; i += 256) {
    int n = n0 + i/qpr, qd = i & (qpr - 1);
    uint4 u = *(const uint4*)&y[((size_t)n*C + c)*T + qd*8];
    float v0 = bflo(u.x), v1 = bfhi(u.x), v2 = bflo(u.y), v3 = bfhi(u.y);
    float v4 = bflo(u.z), v5 = bfhi(u.z), v6 = bflo(u.w), v7 = bfhi(u.w);
    s += (v0+v1)+(v2+v3)+((v4+v5)+(v6+v7));
    q += (v0*v0+v1*v1)+(v2*v2+v3*v3)+((v4*v4+v5*v5)+(v6*v6+v7*v7));
  }
  __shared__ float rs[256], rq[256];
  rs[tid] = s; rq[tid] = q; __syncthreads();
  for (int off = 128; off > 0; off >>= 1) {
    if (tid < off) { rs[tid] += rs[tid+off]; rq[tid] += rq[tid+off]; }
    __syncthreads();
  }
  if (tid == 0) { atomicAdd(&stat[c], rs[0]); atomicAdd(&stat[128+c], rq[0]); }
}

__global__ void bn_finalize_kernel(float* __restrict__ stat, const float* __restrict__ g,
                                   const float* __restrict__ b, int C, float invCnt)
{
  int c = threadIdx.x;
  if (c < C) {
    float m  = stat[c]*invCnt;
    float v  = stat[128+c]*invCnt - m*m;
    float sc = g[c]*rsqrtf(v + 1e-5f);
    stat[256+c] = sc;
    stat[384+c] = b[c] - m*sc;
  }
}

// ---------------- BN apply + ReLU + maxpool2 + transpose ----------------
template<int C, int TH>
__global__ __launch_bounds__(256) void poolT_kernel(
    const bf16* __restrict__ yin, const float* __restrict__ stat, bf16* __restrict__ outp)
{
  __shared__ bf16 buf[C][TH + 2];
  const int n = blockIdx.x, tid = threadIdx.x;
  const uint* src = (const uint*)(yin + (size_t)n*C*TH*2);
  for (int i = tid; i < C*TH; i += 256) {
    int th = i & (TH - 1), c = i / TH;
    uint u = src[i];
    float sc = stat[256 + c], sh = stat[384 + c];
    float a = fmaxf(sc*bflo(u) + sh, 0.f);
    float b = fmaxf(sc*bfhi(u) + sh, 0.f);
    buf[c][th] = (bf16)fmaxf(a, b);
  }
  __syncthreads();
  bf16* dst = outp + (size_t)n*TH*C;
  for (int i = tid; i < TH*C/2; i += 256) {
    int cp = i & (C/2 - 1), th = i / (C/2);
    union { bf16 h[2]; uint u; } pk;
    pk.h[0] = buf[2*cp][th]; pk.h[1] = buf[2*cp + 1][th];
    *(uint*)&dst[th*C + 2*cp] = pk.u;
  }
}

// ---------------- fused biLSTM, operand-swapped: gates land in acc regs ----------------
// grid 256 = (128 node-groups x 2 dirs), block 512 = 8 waves; wave wv owns gate-cols
// [wv*64, wv*64+64). mfma16(weight_frag, x/h_frag, acc): col=node=lane&15,
// row=c=lh*4+reg -> per lane the 4 regs are gates i,f,g,o of (node=l15, hh=wv*16+cf*4+lh).
// h double-buffered in LDS -> 1 barrier/t; inproj(t+1) MFMAs issued after nonlin (overlap).
__global__ __launch_bounds__(512, 2) void lstm_fused_kernel(
    const bf16* __restrict__ p2t, const bf16* __restrict__ wih_g,
    const bf16* __restrict__ whh_g, const float* __restrict__ bias_g,
    float* __restrict__ hsum)
{
  __shared__ bf16 hb[2][2048];   // [buf][16 n][128 hh], 256B rows, swizzled
  const int z = blockIdx.x;
  const int dir = z & 1, n0 = (z >> 1)*16;
  const int tid = threadIdx.x, lane = tid & 63, wv = tid >> 6;
  const int l15 = lane & 15, lh = lane >> 4;
  i32x4 wihr[4][4], whhr[4][4];
  {
    const bf16* wi = wih_g + (size_t)dir*65536;
    const bf16* wh = whh_g + (size_t)dir*65536;
    #pragma unroll
    for (int cf = 0; cf < 4; ++cf) {
      int c = wv*64 + cf*16 + l15;
      #pragma unroll
      for (int ks = 0; ks < 4; ++ks) {
        wihr[cf][ks] = *(const i32x4*)(wi + (size_t)c*128 + ks*32 + lh*8);
        whhr[cf][ks] = *(const i32x4*)(wh + (size_t)c*128 + ks*32 + lh*8);
      }
    }
  }
  f32x4 bias4[4];
  #pragma unroll
  for (int cf = 0; cf < 4; ++cf) {
    int hh = wv*16 + cf*4 + lh;
    bias4[cf] = *(const f32x4*)&bias_g[dir*512 + hh*4];
  }
  for (int i = tid; i < 256; i += 512) ((i32x4*)hb[0])[i] = (i32x4){0,0,0,0};
  const bf16* xrow = p2t + (size_t)(n0 + l15)*128*128;
  float creg[4] = {0.f,0.f,0.f,0.f}, hac[4] = {0.f,0.f,0.f,0.f};
  f32x4 acc[4];
  i32x4 xn[4];
  { // prologue: acc = bias + x(t=0) @ wih
    int ts0 = dir ? 127 : 0;
    #pragma unroll
    for (int ks = 0; ks < 4; ++ks)
      xn[ks] = *(const i32x4*)(xrow + (size_t)ts0*128 + ks*32 + lh*8);
    #pragma unroll
    for (int cf = 0; cf < 4; ++cf) {
      acc[cf] = mfma16(wihr[cf][0], xn[0], bias4[cf]);
      #pragma unroll
      for (int ks = 1; ks < 4; ++ks)
        acc[cf] = mfma16(wihr[cf][ks], xn[ks], acc[cf]);
    }
  }
  int cur = 0;
  __syncthreads();
  for (int t = 0; t < 128; ++t) {
    { // load x(t+1) early (consumed at iteration end)
      int tn = (t + 1 < 128) ? t + 1 : 127;
      int tsn = dir ? 127 - tn : tn;
      #pragma unroll
      for (int ks = 0; ks < 4; ++ks)
        xn[ks] = *(const i32x4*)(xrow + (size_t)tsn*128 + ks*32 + lh*8);
    }
    // recurrence: acc += h(t-1) @ whh
    i32x4 af[4];
    #pragma unroll
    for (int ks = 0; ks < 4; ++ks)
      af[ks] = *(const i32x4*)swz256((char*)hb[cur], l15, ks*64 + lh*16);
    #pragma unroll
    for (int cf = 0; cf < 4; ++cf)
      #pragma unroll
      for (int ks = 0; ks < 4; ++ks)
        acc[cf] = mfma16(whhr[cf][ks], af[ks], acc[cf]);
    // nonlinearity: regs = gates i,f,g,o directly
    #pragma unroll
    for (int cf = 0; cf < 4; ++cf) {
      float ig = sigf_(acc[cf][0]);
      float fg = sigf_(acc[cf][1]);
      float gg = tanhx_(acc[cf][2]);
      float og = sigf_(acc[cf][3]);
      float cv = fg*creg[cf] + ig*gg;
      creg[cf] = cv;
      float hv = og*tanhx_(cv);
      hac[cf] += hv;
      int hh = wv*16 + cf*4 + lh;
      *(bf16*)swz256((char*)hb[cur^1], l15, hh*2) = (bf16)hv;
    }
    // inproj for t+1 (independent of h; overlaps VALU of other wave / barrier)
    #pragma unroll
    for (int cf = 0; cf < 4; ++cf) {
      acc[cf] = mfma16(wihr[cf][0], xn[0], bias4[cf]);
      #pragma unroll
      for (int ks = 1; ks < 4; ++ks)
        acc[cf] = mfma16(wihr[cf][ks], xn[ks], acc[cf]);
    }
    __syncthreads();
    cur ^= 1;
  }
  float* hm = hsum + ((size_t)dir*2048 + n0)*128;
  #pragma unroll
  for (int cf = 0; cf < 4; ++cf) {
    int hh = wv*16 + cf*4 + lh;
    hm[(size_t)l15*128 + hh] = hac[cf];
  }
}

// ---------------- feats = mean over T of [hf, hr] ----------------
__global__ __launch_bounds__(256) void feats_kernel(const float* __restrict__ hsum, float* __restrict__ feats)
{
  int idx = blockIdx.x*256 + threadIdx.x;
  int k = idx & 255, n = idx >> 8;
  float v = (k < 128) ? hsum[(size_t)n*128 + k]
                      : hsum[(size_t)2048*128 + (size_t)n*128 + (k - 128)];
  feats[idx] = v * 0.0078125f;
}

// ---------------- Wh = in @ W^T  ([2048,K] x [128,K]) ----------------
template<int K>
__global__ __launch_bounds__(256) void node_gemm_kernel(
    const float* __restrict__ inp, const float* __restrict__ W, float* __restrict__ outp)
{
  __shared__ float ft[32][K];
  const int i0 = blockIdx.x*32, tid = threadIdx.x;
  for (int i = tid; i < 32*K; i += 256) ft[i/K][i%K] = inp[(size_t)i0*K + i];
  __syncthreads();
  const int f = tid & 127, ih = (tid >> 7)*16;
  float acc[16];
  #pragma unroll
  for (int ii = 0; ii < 16; ++ii) acc[ii] = 0.f;
  const float* wp = W + (size_t)f*K;
  for (int k = 0; k < K; k += 4) {
    const float4 wv = *reinterpret_cast<const float4*>(&wp[k]);
    #pragma unroll
    for (int ii = 0; ii < 16; ++ii) {
      const float* fp = &ft[ih+ii][k];
      acc[ii] += fp[0]*wv.x + fp[1]*wv.y + fp[2]*wv.z + fp[3]*wv.w;
    }
  }
  #pragma unroll
  for (int ii = 0; ii < 16; ++ii) outp[(size_t)(i0+ih+ii)*128 + f] = acc[ii];
}

// ---------------- s1/s2 per node ----------------
__global__ __launch_bounds__(256) void gat_s_kernel(const float* __restrict__ Wh,
    const float* __restrict__ a, float* __restrict__ s1, float* __restrict__ s2)
{
  const int node = blockIdx.x*4 + (threadIdx.x >> 6);
  const int l = threadIdx.x & 63;
  const float w0 = Wh[(size_t)node*128 + l], w1 = Wh[(size_t)node*128 + 64 + l];
  float v1 = w0*a[l]     + w1*a[64+l];
  float v2 = w0*a[128+l] + w1*a[192+l];
  #pragma unroll
  for (int off = 32; off > 0; off >>= 1) { v1 += __shfl_down(v1, off); v2 += __shfl_down(v2, off); }
  if (l == 0) { s1[node] = v1; s2[node] = v2; }
}

// ---------------- GAT attention row ----------------
__global__ __launch_bounds__(256) void gat_attn_kernel(const float* __restrict__ Wh,
    const float* __restrict__ s1, const float* __restrict__ s2v,
    const int* __restrict__ adj, float* __restrict__ outp, int applyElu)
{
  __shared__ float ebuf[2048];
  __shared__ float red[256];
  const int i = blockIdx.x, tid = threadIdx.x;
  const float s1i = s1[i];
  const int* arow = adj + (size_t)i*2048;
  float ev[8]; float lmax = -3.0e38f;
  #pragma unroll
  for (int r = 0; r < 8; ++r) {
    int j = tid + r*256;
    float e = s1i + s2v[j];
    e = (e > 0.f) ? e : 0.2f*e;
    e = (arow[j] > 0) ? e : -3.0e38f;
    ev[r] = e; lmax = fmaxf(lmax, e);
  }
  red[tid] = lmax; __syncthreads();
  for (int off = 128; off > 0; off >>= 1) { if (tid < off) red[tid] = fmaxf(red[tid], red[tid+off]); __syncthreads(); }
  const float m = red[0]; __syncthreads();
  float lsum = 0.f;
  #pragma unroll
  for (int r = 0; r < 8; ++r) { float pp = __expf(ev[r] - m); ebuf[tid + r*256] = pp; lsum += pp; }
  red[tid] = lsum; __syncthreads();
  for (int off = 128; off > 0; off >>= 1) { if (tid < off) red[tid] += red[tid+off]; __syncthreads(); }
  const float inv = 1.0f/red[0];
  __syncthreads();
  const int f = tid & 127, jh = tid >> 7;
  float acc = 0.f;
  for (int j = 0; j < 1024; ++j) acc += ebuf[jh*1024 + j] * Wh[(size_t)(jh*1024 + j)*128 + f];
  red[tid] = acc; __syncthreads();
  if (tid < 128) {
    float v = (red[tid] + red[tid+128])*inv;
    if (applyElu) v = (v > 0.f) ? v : (__expf(v) - 1.0f);
    outp[(size_t)i*128 + tid] = v;
  }
}

// ---------------- launch ----------------
extern "C" void kernel_launch(void* const* d_in, const int* in_sizes, int n_in,
                              void* d_out, int out_size, void* d_ws, size_t ws_size,
                              hipStream_t stream)
{
  (void)in_sizes; (void)n_in; (void)out_size; (void)ws_size;
  const float* x    = (const float*)d_in[0];
  const int*   adj  = (const int*)d_in[1];
  const float* c1w  = (const float*)d_in[2];
  const float* c1b  = (const float*)d_in[3];
  const float* bn1g = (const float*)d_in[4];
  const float* bn1b = (const float*)d_in[5];
  const float* c2w  = (const float*)d_in[6];
  const float* c2b  = (const float*)d_in[7];
  const float* bn2g = (const float*)d_in[8];
  const float* bn2b = (const float*)d_in[9];
  const float* wif  = (const float*)d_in[10];
  const float* whf  = (const float*)d_in[11];
  const float* bfv  = (const float*)d_in[12];
  const float* wir  = (const float*)d_in[13];
  const float* whr  = (const float*)d_in[14];
  const float* brv  = (const float*)d_in[15];
  const float* g1W  = (const float*)d_in[16];
  const float* g1a  = (const float*)d_in[17];
  const float* g2W  = (const float*)d_in[18];
  const float* g2a  = (const float*)d_in[19];
  float* outp = (float*)d_out;
  float* ws   = (float*)d_ws;

  bf16* y12    = (bf16*)(ws + OFF_A);
  bf16* pool1t = (bf16*)(ws + OFF_B);      // [2048][256][64]
  bf16* pool2t = (bf16*)(ws + OFF_B1);     // [2048][128][128]
  bf16* whh_g  = (bf16*)(ws + OFF_WHHG);
  bf16* wih_g  = (bf16*)(ws + OFF_WIHG);
  float* bias_g= ws + OFF_BIAS;
  float* hsm   = ws + OFF_HSUM;
  float* feats = ws + OFF_FEAT;
  float* Wh1   = ws + OFF_WH1;
  float* s1a   = ws + OFF_S1A;
  float* s2a   = ws + OFF_S2A;
  float* h1    = ws + OFF_H1;
  float* Wh2   = ws + OFF_WH2;
  float* s1b   = ws + OFF_S1B;
  float* s2b   = ws + OFF_S2B;
  float* stat  = ws + OFF_STAT;
  bf16* w1p    = (bf16*)(ws + OFF_W1P);
  bf16* w2p    = (bf16*)(ws + OFF_W2P);

  hipMemsetAsync(stat, 0, 512*sizeof(float), stream);

  prep_kernel<<<dim3(256,2),256,0,stream>>>(whf, whr, wif, wir, bfv, brv, c1w, c2w,
                                            whh_g, wih_g, bias_g, w1p, w2p);

  // conv1 -> BN -> relu -> pool (+transpose)
  conv1_kernel<<<dim3(2,2048),512,0,stream>>>(x, w1p, c1b, y12);
  bn_stats_kernel<<<dim3(64,32),256,0,stream>>>(y12, stat, 64, 512);
  bn_finalize_kernel<<<1,128,0,stream>>>(stat, bn1g, bn1b, 64, 1.0f/(2048.0f*512.0f));
  poolT_kernel<64,256><<<2048,256,0,stream>>>(y12, stat, pool1t);

  // conv2 -> BN -> relu -> pool (+transpose)
  hipMemsetAsync(stat, 0, 256*sizeof(float), stream);
  conv2_kernel<<<2048,512,0,stream>>>(pool1t, w2p, c2b, y12);
  bn_stats_kernel<<<dim3(128,32),256,0,stream>>>(y12, stat, 128, 256);
  bn_finalize_kernel<<<1,128,0,stream>>>(stat, bn2g, bn2b, 128, 1.0f/(2048.0f*256.0f));
  poolT_kernel<128,128><<<2048,256,0,stream>>>(y12, stat, pool2t);

  // fused biLSTM (single dispatch)
  lstm_fused_kernel<<<256,512,0,stream>>>(pool2t, wih_g, whh_g, bias_g, hsm);
  feats_kernel<<<2048,256,0,stream>>>(hsm, feats);

  // GAT x2
  node_gemm_kernel<256><<<64,256,0,stream>>>(feats, g1W, Wh1);
  gat_s_kernel<<<512,256,0,stream>>>(Wh1, g1a, s1a, s2a);
  gat_attn_kernel<<<2048,256,0,stream>>>(Wh1, s1a, s2a, adj, h1, 1);
  node_gemm_kernel<128><<<64,256,0,stream>>>(h1, g2W, Wh2);
  gat_s_kernel<<<512,256,0,stream>>>(Wh2, g2a, s1b, s2b);
  gat_attn_kernel<<<2048,256,0,stream>>>(Wh2, s1b, s2b, adj, outp, 0);
}

// Round 6
// 716.479 us; speedup vs baseline: 5.8466x; 1.0049x over previous
//
#include <hip/hip_runtime.h>

typedef unsigned int uint;
#define DI __device__ __forceinline__

typedef __bf16 bf16;
typedef __attribute__((ext_vector_type(4))) float f32x4;
typedef __attribute__((ext_vector_type(8))) __bf16 bf16x8;
typedef __attribute__((ext_vector_type(4))) int i32x4;

// ---------------- ws layout (float units) ----------------
constexpr size_t OFF_A    = 0;                    // y1/y2 bf16 [N][C][T]
constexpr size_t OFF_B    = 33554432;             // pool1t bf16
constexpr size_t OFF_B1   = OFF_B + 16777216;     // pool2t bf16 [2048][128][128]
constexpr size_t OFF_WHHG = 67108864;             // bf16 [2][512][128]
constexpr size_t OFF_WIHG = OFF_WHHG + 65536;     // bf16 [2][512][128]
constexpr size_t OFF_BIAS = OFF_WIHG + 65536;     // f32 [2][512]
constexpr size_t OFF_HSUM = OFF_BIAS + 1024;      // f32 [2][2048][128]
constexpr size_t OFF_FEAT = OFF_HSUM + 524288;    // f32 [2048][256]
constexpr size_t OFF_WH1  = OFF_FEAT + 524288;    // f32 [2048][128]
constexpr size_t OFF_S1A  = OFF_WH1 + 262144;
constexpr size_t OFF_S2A  = OFF_S1A + 2048;
constexpr size_t OFF_H1   = OFF_S2A + 2048;
constexpr size_t OFF_WH2  = OFF_H1 + 262144;
constexpr size_t OFF_S1B  = OFF_WH2 + 262144;
constexpr size_t OFF_S2B  = OFF_S1B + 2048;
constexpr size_t OFF_STAT = OFF_S2B + 2048;       // sum/sumsq/scale/shift
constexpr size_t OFF_W1P  = OFF_STAT + 512;       // bf16 12288 (pre-swizzled conv1 w)
constexpr size_t OFF_W2P  = OFF_W1P + 6144;       // bf16 24576 (pre-swizzled conv2 w)
constexpr size_t OFF_WHT  = OFF_W2P + 12288;      // bf16 [128][2048] (WhT, reused both layers)

DI float bflo(uint u){ union { uint i; float f; } v; v.i = u << 16;         return v.f; }
DI float bfhi(uint u){ union { uint i; float f; } v; v.i = u & 0xffff0000u; return v.f; }
DI float fexp2_(float x){ return __builtin_amdgcn_exp2f(x); }
DI float frcp_(float x){ return __builtin_amdgcn_rcpf(x); }
DI float sigf_(float x){ return frcp_(1.0f + fexp2_(x * -1.44269504f)); }
// tanh(x) = 1 - 2/(e^{2x}+1); saturates correctly at +/-inf
DI float tanhx_(float x){ return 1.0f - 2.0f*frcp_(1.0f + fexp2_(x * 2.88539009f)); }

DI f32x4 mfma16(i32x4 a, i32x4 b, f32x4 c){
  return __builtin_amdgcn_mfma_f32_16x16x32_bf16(
      __builtin_bit_cast(bf16x8, a), __builtin_bit_cast(bf16x8, b), c, 0, 0, 0);
}

// swizzled LDS address helpers (XOR bits[4:6] by row&7)
DI char* swz128(char* base, int row, int byteInRow){ return base + row*128 + (byteInRow ^ ((row&7)<<4)); }
DI char* swz256(char* base, int row, int byteInRow){ return base + row*256 + (byteInRow ^ ((row&7)<<4)); }

// ---------------- prep: gate-interleaved LSTM weights + pre-swizzled conv weights ----------------
__global__ void prep_kernel(const float* __restrict__ whf, const float* __restrict__ whr,
                            const float* __restrict__ wif, const float* __restrict__ wir,
                            const float* __restrict__ bfv, const float* __restrict__ brv,
                            const float* __restrict__ c1w, const float* __restrict__ c2w,
                            bf16* __restrict__ whh_g, bf16* __restrict__ wih_g,
                            float* __restrict__ bias_g,
                            bf16* __restrict__ w1p, bf16* __restrict__ w2p)
{
  const int dir = blockIdx.y;
  const float* whh = dir ? whr : whf;
  const float* wih = dir ? wir : wif;
  const float* bb  = dir ? brv : bfv;
  int idx = blockIdx.x*256 + threadIdx.x;        // < 65536
  int c = idx >> 7, d = idx & 127;
  int src = ((c & 3)*128 + (c >> 2))*128 + d;
  whh_g[(size_t)dir*65536 + idx] = (bf16)whh[src];
  wih_g[(size_t)dir*65536 + idx] = (bf16)wih[src];
  if (idx < 512) bias_g[dir*512 + idx] = bb[(idx & 3)*128 + (idx >> 2)];
  if (dir == 0) {
    if (idx < 12288) {
      int row = idx >> 6;
      int ci = (((idx & 63)*2) ^ ((row & 7) << 4)) >> 1;
      int co = row & 63, dk = row >> 6;
      w1p[idx] = (bf16)c1w[(co*64 + ci)*3 + dk];
    }
    if (idx < 24576) {
      int row = idx >> 6;
      int ci = (((idx & 63)*2) ^ ((row & 7) << 4)) >> 1;
      int co = row & 127, dk = row >> 7;
      w2p[idx] = (bf16)c2w[(co*64 + ci)*3 + dk];
    }
  }
}

// ---------------- conv1: x f32 [2048][64][512] -> y1 bf16 [2048][64][512] ----------------
__global__ __launch_bounds__(512) void conv1_kernel(
    const float* __restrict__ x, const bf16* __restrict__ w1p,
    const float* __restrict__ bias, bf16* __restrict__ y)
{
  __shared__ bf16 xa[258*64];     // [row=t-t0+1][ci], 128B rows, swizzled
  __shared__ bf16 wb[3*64*64];    // [dk*64+co][ci], swizzled (pre-swizzled copy)
  const int n = blockIdx.y, t0 = blockIdx.x*256, tid = threadIdx.x;
  {
    const i32x4* wsrc = (const i32x4*)w1p;
    for (int i = tid; i < 1536; i += 512) ((i32x4*)wb)[i] = wsrc[i];
  }
  for (int i = tid; i < 4096; i += 512) {
    int q = i & 63, ci = i >> 6;
    float4 v = *(const float4*)&x[((size_t)n*64 + ci)*512 + t0 + q*4];
    int row = q*4 + 1;
    *(bf16*)swz128((char*)xa, row+0, ci*2) = (bf16)v.x;
    *(bf16*)swz128((char*)xa, row+1, ci*2) = (bf16)v.y;
    *(bf16*)swz128((char*)xa, row+2, ci*2) = (bf16)v.z;
    *(bf16*)swz128((char*)xa, row+3, ci*2) = (bf16)v.w;
  }
  if (tid < 128) {
    int ci = tid >> 1, e = tid & 1;
    int row = e ? 257 : 0;
    int t = t0 + (e ? 256 : -1);
    float v = (t >= 0 && t < 512) ? x[((size_t)n*64 + ci)*512 + t] : 0.0f;
    *(bf16*)swz128((char*)xa, row, ci*2) = (bf16)v;
  }
  __syncthreads();
  const int lane = tid & 63, wv = tid >> 6;
  const int m0 = (wv & 3)*64, c0 = (wv >> 2)*32;
  const int l15 = lane & 15, lh = lane >> 4;
  f32x4 acc[4][2];
  #pragma unroll
  for (int mf = 0; mf < 4; ++mf)
    #pragma unroll
    for (int cf = 0; cf < 2; ++cf) {
      float bb = bias[c0 + cf*16 + l15];
      acc[mf][cf] = (f32x4){bb, bb, bb, bb};
    }
  #pragma unroll
  for (int dk = 0; dk < 3; ++dk)
    #pragma unroll
    for (int ks = 0; ks < 2; ++ks) {
      const int kb = ks*64 + lh*16;
      i32x4 bfr[2], afr[4];
      #pragma unroll
      for (int cf = 0; cf < 2; ++cf) {
        int row = dk*64 + c0 + cf*16 + l15;
        bfr[cf] = *(const i32x4*)swz128((char*)wb, row, kb);
      }
      #pragma unroll
      for (int mf = 0; mf < 4; ++mf) {
        int row = m0 + mf*16 + l15 + dk;
        afr[mf] = *(const i32x4*)swz128((char*)xa, row, kb);
      }
      #pragma unroll
      for (int mf = 0; mf < 4; ++mf)
        #pragma unroll
        for (int cf = 0; cf < 2; ++cf)
          acc[mf][cf] = mfma16(afr[mf], bfr[cf], acc[mf][cf]);
    }
  #pragma unroll
  for (int mf = 0; mf < 4; ++mf)
    #pragma unroll
    for (int cf = 0; cf < 2; ++cf) {
      int co = c0 + cf*16 + l15;
      int tt = t0 + m0 + mf*16 + lh*4;
      union { bf16 h[4]; uint2 u; } pk;
      #pragma unroll
      for (int r = 0; r < 4; ++r) pk.h[r] = (bf16)acc[mf][cf][r];
      *(uint2*)&y[((size_t)n*64 + co)*512 + tt] = pk.u;
    }
}

// ---------------- conv2: pool1T bf16 [2048][256][64] -> y2 bf16 [2048][128][256] ----------------
__global__ __launch_bounds__(512) void conv2_kernel(
    const bf16* __restrict__ xin, const bf16* __restrict__ w2p,
    const float* __restrict__ bias, bf16* __restrict__ y)
{
  __shared__ bf16 xa[258*64];
  __shared__ bf16 wb[3*128*64];
  const int n = blockIdx.x, tid = threadIdx.x;
  {
    const i32x4* wsrc = (const i32x4*)w2p;
    for (int i = tid; i < 3072; i += 512) ((i32x4*)wb)[i] = wsrc[i];
  }
  {
    const i32x4* src = (const i32x4*)(xin + (size_t)n*256*64);
    for (int i = tid; i < 2048; i += 512) {
      int row = (i >> 3) + 1, blk = i & 7;
      *(i32x4*)swz128((char*)xa, row, blk*16) = src[i];
    }
  }
  if (tid < 128) {
    int ci = tid >> 1, e = tid & 1;
    int row = e ? 257 : 0;
    *(bf16*)swz128((char*)xa, row, ci*2) = (bf16)0.0f;
  }
  __syncthreads();
  const int lane = tid & 63, wv = tid >> 6;
  const int m0 = (wv & 3)*64, c0 = (wv >> 2)*64;
  const int l15 = lane & 15, lh = lane >> 4;
  f32x4 acc[4][4];
  #pragma unroll
  for (int mf = 0; mf < 4; ++mf)
    #pragma unroll
    for (int cf = 0; cf < 4; ++cf) {
      float bb = bias[c0 + cf*16 + l15];
      acc[mf][cf] = (f32x4){bb, bb, bb, bb};
    }
  #pragma unroll
  for (int dk = 0; dk < 3; ++dk)
    #pragma unroll
    for (int ks = 0; ks < 2; ++ks) {
      const int kb = ks*64 + lh*16;
      i32x4 bfr[4], afr[4];
      #pragma unroll
      for (int cf = 0; cf < 4; ++cf) {
        int row = dk*128 + c0 + cf*16 + l15;
        bfr[cf] = *(const i32x4*)swz128((char*)wb, row, kb);
      }
      #pragma unroll
      for (int mf = 0; mf < 4; ++mf) {
        int row = m0 + mf*16 + l15 + dk;
        afr[mf] = *(const i32x4*)swz128((char*)xa, row, kb);
      }
      #pragma unroll
      for (int mf = 0; mf < 4; ++mf)
        #pragma unroll
        for (int cf = 0; cf < 4; ++cf)
          acc[mf][cf] = mfma16(afr[mf], bfr[cf], acc[mf][cf]);
    }
  #pragma unroll
  for (int mf = 0; mf < 4; ++mf)
    #pragma unroll
    for (int cf = 0; cf < 4; ++cf) {
      int co = c0 + cf*16 + l15;
      int tt = m0 + mf*16 + lh*4;
      union { bf16 h[4]; uint2 u; } pk;
      #pragma unroll
      for (int r = 0; r < 4; ++r) pk.h[r] = (bf16)acc[mf][cf][r];
      *(uint2*)&y[((size_t)n*128 + co)*256 + tt] = pk.u;
    }
}

// ---------------- BN stats (vectorized uint4 loads) ----------------
__global__ __launch_bounds__(256) void bn_stats_kernel(
    const bf16* __restrict__ y, float* __restrict__ stat, int C, int T)
{
  const int c = blockIdx.x, n0 = blockIdx.y*64, tid = threadIdx.x;
  float s = 0.f, q = 0.f;
  const int qpr = T >> 3;           // uint4 (8 bf16) per row
  for (int i = tid; i < 64*qpr; i += 256) {
    int n = n0 + i/qpr, qd = i & (qpr - 1);
    uint4 u = *(const uint4*)&y[((size_t)n*C + c)*T + qd*8];
    float v0 = bflo(u.x), v1 = bfhi(u.x), v2 = bflo(u.y), v3 = bfhi(u.y);
    float v4 = bflo(u.z), v5 = bfhi(u.z), v6 = bflo(u.w), v7 = bfhi(u.w);
    s += (v0+v1)+(v2+v3)+((v4+v5)+(v6+v7));
    q += (v0*v0+v1*v1)+(v2*v2+v3*v3)+((v4*v4+v5*v5)+(v6*v6+v7*v7));
  }
  __shared__ float rs[256], rq[256];
  rs[tid] = s; rq[tid] = q; __syncthreads();
  for (int off = 128; off > 0; off >>= 1) {
    if (tid < off) { rs[tid] += rs[tid+off]; rq[tid] += rq[tid+off]; }
    __syncthreads();
  }
  if (tid == 0) { atomicAdd(&stat[c], rs[0]); atomicAdd(&stat[128+c], rq[0]); }
}

__global__ void bn_finalize_kernel(float* __restrict__ stat, const float* __restrict__ g,
                                   const float* __restrict__ b, int C, float invCnt)
{
  int c = threadIdx.x;
  if (c < C) {
    float m  = stat[c]*invCnt;
    float v  = stat[128+c]*invCnt - m*m;
    float sc = g[c]*rsqrtf(v + 1e-5f);
    stat[256+c] = sc;
    stat[384+c] = b[c] - m*sc;
  }
}

// ---------------- BN apply + ReLU + maxpool2 + transpose ----------------
template<int C, int TH>
__global__ __launch_bounds__(256) void poolT_kernel(
    const bf16* __restrict__ yin, const float* __restrict__ stat, bf16* __restrict__ outp)
{
  __shared__ bf16 buf[C][TH + 2];
  const int n = blockIdx.x, tid = threadIdx.x;
  const uint* src = (const uint*)(yin + (size_t)n*C*TH*2);
  for (int i = tid; i < C*TH; i += 256) {
    int th = i & (TH - 1), c = i / TH;
    uint u = src[i];
    float sc = stat[256 + c], sh = stat[384 + c];
    float a = fmaxf(sc*bflo(u) + sh, 0.f);
    float b = fmaxf(sc*bfhi(u) + sh, 0.f);
    buf[c][th] = (bf16)fmaxf(a, b);
  }
  __syncthreads();
  bf16* dst = outp + (size_t)n*TH*C;
  for (int i = tid; i < TH*C/2; i += 256) {
    int cp = i & (C/2 - 1), th = i / (C/2);
    union { bf16 h[2]; uint u; } pk;
    pk.h[0] = buf[2*cp][th]; pk.h[1] = buf[2*cp + 1][th];
    *(uint*)&dst[th*C + 2*cp] = pk.u;
  }
}

// ---------------- fused biLSTM: 16 waves/block (4/SIMD), cf=2 per thread ----------------
// grid 256 = (128 node-groups x 2 dirs), block 1024. Wave wv owns gate-cols
// [wv*32, wv*32+32). mfma16(weight, x/h): per lane regs = gates i,f,g,o of
// (node=l15, hh=wv*8+cf*4+lh). h double-buffered in 8KB LDS; 1 barrier/t.
__global__ __launch_bounds__(1024, 4) void lstm_fused_kernel(
    const bf16* __restrict__ p2t, const bf16* __restrict__ wih_g,
    const bf16* __restrict__ whh_g, const float* __restrict__ bias_g,
    float* __restrict__ hsum)
{
  __shared__ bf16 hb[2][2048];   // [buf][16 n][128 hh], 256B rows, swizzled
  const int z = blockIdx.x;
  const int dir = z & 1, n0 = (z >> 1)*16;
  const int tid = threadIdx.x, lane = tid & 63, wv = tid >> 6;   // wv < 16
  const int l15 = lane & 15, lh = lane >> 4;
  i32x4 wihr[2][4], whhr[2][4];
  {
    const bf16* wi = wih_g + (size_t)dir*65536;
    const bf16* wh = whh_g + (size_t)dir*65536;
    #pragma unroll
    for (int cf = 0; cf < 2; ++cf) {
      int c = wv*32 + cf*16 + l15;
      #pragma unroll
      for (int ks = 0; ks < 4; ++ks) {
        wihr[cf][ks] = *(const i32x4*)(wi + (size_t)c*128 + ks*32 + lh*8);
        whhr[cf][ks] = *(const i32x4*)(wh + (size_t)c*128 + ks*32 + lh*8);
      }
    }
  }
  f32x4 bias4[2];
  #pragma unroll
  for (int cf = 0; cf < 2; ++cf) {
    int hh = wv*8 + cf*4 + lh;
    bias4[cf] = *(const f32x4*)&bias_g[dir*512 + hh*4];
  }
  for (int i = tid; i < 256; i += 1024) ((i32x4*)hb[0])[i] = (i32x4){0,0,0,0};
  const bf16* xrow = p2t + (size_t)(n0 + l15)*128*128;
  float creg[2] = {0.f,0.f}, hac[2] = {0.f,0.f};
  f32x4 acc[2];
  i32x4 xn[4];
  { // prologue: acc = bias + x(t=0) @ wih
    int ts0 = dir ? 127 : 0;
    #pragma unroll
    for (int ks = 0; ks < 4; ++ks)
      xn[ks] = *(const i32x4*)(xrow + (size_t)ts0*128 + ks*32 + lh*8);
    #pragma unroll
    for (int cf = 0; cf < 2; ++cf) {
      acc[cf] = mfma16(wihr[cf][0], xn[0], bias4[cf]);
      #pragma unroll
      for (int ks = 1; ks < 4; ++ks)
        acc[cf] = mfma16(wihr[cf][ks], xn[ks], acc[cf]);
    }
  }
  int cur = 0;
  __syncthreads();
  for (int t = 0; t < 128; ++t) {
    { // load x(t+1) early (consumed after nonlin)
      int tn = (t + 1 < 128) ? t + 1 : 127;
      int tsn = dir ? 127 - tn : tn;
      #pragma unroll
      for (int ks = 0; ks < 4; ++ks)
        xn[ks] = *(const i32x4*)(xrow + (size_t)tsn*128 + ks*32 + lh*8);
    }
    // recurrence: acc += h(t-1) @ whh (paired af loads to save regs)
    {
      i32x4 a0 = *(const i32x4*)swz256((char*)hb[cur], l15, 0*64 + lh*16);
      i32x4 a1 = *(const i32x4*)swz256((char*)hb[cur], l15, 1*64 + lh*16);
      #pragma unroll
      for (int cf = 0; cf < 2; ++cf) {
        acc[cf] = mfma16(whhr[cf][0], a0, acc[cf]);
        acc[cf] = mfma16(whhr[cf][1], a1, acc[cf]);
      }
      a0 = *(const i32x4*)swz256((char*)hb[cur], l15, 2*64 + lh*16);
      a1 = *(const i32x4*)swz256((char*)hb[cur], l15, 3*64 + lh*16);
      #pragma unroll
      for (int cf = 0; cf < 2; ++cf) {
        acc[cf] = mfma16(whhr[cf][2], a0, acc[cf]);
        acc[cf] = mfma16(whhr[cf][3], a1, acc[cf]);
      }
    }
    // nonlinearity: regs = gates i,f,g,o directly
    #pragma unroll
    for (int cf = 0; cf < 2; ++cf) {
      float ig = sigf_(acc[cf][0]);
      float fg = sigf_(acc[cf][1]);
      float gg = tanhx_(acc[cf][2]);
      float og = sigf_(acc[cf][3]);
      float cv = fg*creg[cf] + ig*gg;
      creg[cf] = cv;
      float hv = og*tanhx_(cv);
      hac[cf] += hv;
      int hh = wv*8 + cf*4 + lh;
      *(bf16*)swz256((char*)hb[cur^1], l15, hh*2) = (bf16)hv;
    }
    // inproj for t+1
    #pragma unroll
    for (int cf = 0; cf < 2; ++cf) {
      acc[cf] = mfma16(wihr[cf][0], xn[0], bias4[cf]);
      #pragma unroll
      for (int ks = 1; ks < 4; ++ks)
        acc[cf] = mfma16(wihr[cf][ks], xn[ks], acc[cf]);
    }
    __syncthreads();
    cur ^= 1;
  }
  float* hm = hsum + ((size_t)dir*2048 + n0)*128;
  #pragma unroll
  for (int cf = 0; cf < 2; ++cf) {
    int hh = wv*8 + cf*4 + lh;
    hm[(size_t)l15*128 + hh] = hac[cf];
  }
}

// ---------------- feats = mean over T of [hf, hr] ----------------
__global__ __launch_bounds__(256) void feats_kernel(const float* __restrict__ hsum, float* __restrict__ feats)
{
  int idx = blockIdx.x*256 + threadIdx.x;
  int k = idx & 255, n = idx >> 8;
  float v = (k < 128) ? hsum[(size_t)n*128 + k]
                      : hsum[(size_t)2048*128 + (size_t)n*128 + (k - 128)];
  feats[idx] = v * 0.0078125f;
}

// ---------------- Wh = in @ W^T  ([2048,K] x [128,K]); also emits WhT bf16 [128][2048] ----------------
template<int K>
__global__ __launch_bounds__(256) void node_gemm_kernel(
    const float* __restrict__ inp, const float* __restrict__ W,
    float* __restrict__ outp, bf16* __restrict__ outT)
{
  __shared__ float ft[32][K];
  const int i0 = blockIdx.x*32, tid = threadIdx.x;
  for (int i = tid; i < 32*K; i += 256) ft[i/K][i%K] = inp[(size_t)i0*K + i];
  __syncthreads();
  const int f = tid & 127, ih = (tid >> 7)*16;
  float acc[16];
  #pragma unroll
  for (int ii = 0; ii < 16; ++ii) acc[ii] = 0.f;
  const float* wp = W + (size_t)f*K;
  for (int k = 0; k < K; k += 4) {
    const float4 wv = *reinterpret_cast<const float4*>(&wp[k]);
    #pragma unroll
    for (int ii = 0; ii < 16; ++ii) {
      const float* fp = &ft[ih+ii][k];
      acc[ii] += fp[0]*wv.x + fp[1]*wv.y + fp[2]*wv.z + fp[3]*wv.w;
    }
  }
  union { bf16 h[16]; uint4 u[2]; } pk;
  #pragma unroll
  for (int ii = 0; ii < 16; ++ii) {
    outp[(size_t)(i0+ih+ii)*128 + f] = acc[ii];
    pk.h[ii] = (bf16)acc[ii];
  }
  uint4* dT = (uint4*)&outT[(size_t)f*2048 + i0 + ih];
  dT[0] = pk.u[0]; dT[1] = pk.u[1];
}

// ---------------- s1/s2 per node ----------------
__global__ __launch_bounds__(256) void gat_s_kernel(const float* __restrict__ Wh,
    const float* __restrict__ a, float* __restrict__ s1, float* __restrict__ s2)
{
  const int node = blockIdx.x*4 + (threadIdx.x >> 6);
  const int l = threadIdx.x & 63;
  const float w0 = Wh[(size_t)node*128 + l], w1 = Wh[(size_t)node*128 + 64 + l];
  float v1 = w0*a[l]     + w1*a[64+l];
  float v2 = w0*a[128+l] + w1*a[192+l];
  #pragma unroll
  for (int off = 32; off > 0; off >>= 1) { v1 += __shfl_down(v1, off); v2 += __shfl_down(v2, off); }
  if (l == 0) { s1[node] = v1; s2[node] = v2; }
}

// ---------------- GAT attention, 16 rows/block, MFMA aggregation ----------------
// Phase 1: wave w computes softmax rows w*2, w*2+1 into P (bf16, 64KB swizzled LDS).
// Phase 2: wave w computes out[16 rows][f-tile w*16..w*16+16) = P @ WhT via 64 MFMA.
__global__ __launch_bounds__(512) void gat_attn16_kernel(
    const bf16* __restrict__ WhT,
    const float* __restrict__ s1, const float* __restrict__ s2v,
    const int* __restrict__ adj, float* __restrict__ outp, int applyElu)
{
  __shared__ bf16 P[16*2048];     // rows of 4096B, swizzled
  __shared__ float sums[16];
  const int i0 = blockIdx.x*16, tid = threadIdx.x;
  const int lane = tid & 63, w = tid >> 6;
  for (int rr = 0; rr < 2; ++rr) {
    const int r = w*2 + rr, i = i0 + r;
    const float s1i = s1[i];
    const int4* arow = (const int4*)(adj + (size_t)i*2048);
    float ev[8][4];
    float m = -3.0e38f;
    #pragma unroll
    for (int k = 0; k < 8; ++k) {
      int4 ad = arow[k*64 + lane];
      float4 sv = *(const float4*)&s2v[k*256 + lane*4];
      float e0 = s1i + sv.x; e0 = (e0 > 0.f) ? e0 : 0.2f*e0; e0 = (ad.x > 0) ? e0 : -3.0e38f;
      float e1 = s1i + sv.y; e1 = (e1 > 0.f) ? e1 : 0.2f*e1; e1 = (ad.y > 0) ? e1 : -3.0e38f;
      float e2 = s1i + sv.z; e2 = (e2 > 0.f) ? e2 : 0.2f*e2; e2 = (ad.z > 0) ? e2 : -3.0e38f;
      float e3 = s1i + sv.w; e3 = (e3 > 0.f) ? e3 : 0.2f*e3; e3 = (ad.w > 0) ? e3 : -3.0e38f;
      ev[k][0]=e0; ev[k][1]=e1; ev[k][2]=e2; ev[k][3]=e3;
      m = fmaxf(m, fmaxf(fmaxf(e0,e1), fmaxf(e2,e3)));
    }
    #pragma unroll
    for (int off = 32; off > 0; off >>= 1) m = fmaxf(m, __shfl_xor(m, off));
    float s = 0.f;
    char* prow = (char*)P + r*4096;
    #pragma unroll
    for (int k = 0; k < 8; ++k) {
      float p0 = __expf(ev[k][0] - m);
      float p1 = __expf(ev[k][1] - m);
      float p2 = __expf(ev[k][2] - m);
      float p3 = __expf(ev[k][3] - m);
      s += (p0+p1)+(p2+p3);
      union { bf16 h[4]; uint2 u; } pk;
      pk.h[0]=(bf16)p0; pk.h[1]=(bf16)p1; pk.h[2]=(bf16)p2; pk.h[3]=(bf16)p3;
      *(uint2*)(prow + ((k*512 + lane*8) ^ ((r&7)<<4))) = pk.u;
    }
    #pragma unroll
    for (int off = 32; off > 0; off >>= 1) s += __shfl_xor(s, off);
    if (lane == 0) sums[r] = s;
  }
  __syncthreads();
  const int l15 = lane & 15, lh = lane >> 4;
  const bf16* bT = WhT + (size_t)(w*16 + l15)*2048;
  f32x4 ac[4];
  #pragma unroll
  for (int q = 0; q < 4; ++q) ac[q] = (f32x4){0.f,0.f,0.f,0.f};
  for (int kt = 0; kt < 64; kt += 4) {
    #pragma unroll
    for (int q = 0; q < 4; ++q) {
      i32x4 af = *(const i32x4*)((char*)P + l15*4096 + (((kt+q)*64 + lh*16) ^ ((l15&7)<<4)));
      i32x4 bf = *(const i32x4*)(bT + (kt+q)*32 + lh*8);
      ac[q] = mfma16(af, bf, ac[q]);
    }
  }
  f32x4 accv = (ac[0] + ac[1]) + (ac[2] + ac[3]);
  #pragma unroll
  for (int rg = 0; rg < 4; ++rg) {
    int i = i0 + lh*4 + rg;
    float v = accv[rg] / sums[lh*4 + rg];
    if (applyElu) v = (v > 0.f) ? v : (__expf(v) - 1.0f);
    outp[(size_t)i*128 + w*16 + l15] = v;
  }
}

// ---------------- launch ----------------
extern "C" void kernel_launch(void* const* d_in, const int* in_sizes, int n_in,
                              void* d_out, int out_size, void* d_ws, size_t ws_size,
                              hipStream_t stream)
{
  (void)in_sizes; (void)n_in; (void)out_size; (void)ws_size;
  const float* x    = (const float*)d_in[0];
  const int*   adj  = (const int*)d_in[1];
  const float* c1w  = (const float*)d_in[2];
  const float* c1b  = (const float*)d_in[3];
  const float* bn1g = (const float*)d_in[4];
  const float* bn1b = (const float*)d_in[5];
  const float* c2w  = (const float*)d_in[6];
  const float* c2b  = (const float*)d_in[7];
  const float* bn2g = (const float*)d_in[8];
  const float* bn2b = (const float*)d_in[9];
  const float* wif  = (const float*)d_in[10];
  const float* whf  = (const float*)d_in[11];
  const float* bfv  = (const float*)d_in[12];
  const float* wir  = (const float*)d_in[13];
  const float* whr  = (const float*)d_in[14];
  const float* brv  = (const float*)d_in[15];
  const float* g1W  = (const float*)d_in[16];
  const float* g1a  = (const float*)d_in[17];
  const float* g2W  = (const float*)d_in[18];
  const float* g2a  = (const float*)d_in[19];
  float* outp = (float*)d_out;
  float* ws   = (float*)d_ws;

  bf16* y12    = (bf16*)(ws + OFF_A);
  bf16* pool1t = (bf16*)(ws + OFF_B);      // [2048][256][64]
  bf16* pool2t = (bf16*)(ws + OFF_B1);     // [2048][128][128]
  bf16* whh_g  = (bf16*)(ws + OFF_WHHG);
  bf16* wih_g  = (bf16*)(ws + OFF_WIHG);
  float* bias_g= ws + OFF_BIAS;
  float* hsm   = ws + OFF_HSUM;
  float* feats = ws + OFF_FEAT;
  float* Wh1   = ws + OFF_WH1;
  float* s1a   = ws + OFF_S1A;
  float* s2a   = ws + OFF_S2A;
  float* h1    = ws + OFF_H1;
  float* Wh2   = ws + OFF_WH2;
  float* s1b   = ws + OFF_S1B;
  float* s2b   = ws + OFF_S2B;
  float* stat  = ws + OFF_STAT;
  bf16* w1p    = (bf16*)(ws + OFF_W1P);
  bf16* w2p    = (bf16*)(ws + OFF_W2P);
  bf16* whT    = (bf16*)(ws + OFF_WHT);

  hipMemsetAsync(stat, 0, 512*sizeof(float), stream);

  prep_kernel<<<dim3(256,2),256,0,stream>>>(whf, whr, wif, wir, bfv, brv, c1w, c2w,
                                            whh_g, wih_g, bias_g, w1p, w2p);

  // conv1 -> BN -> relu -> pool (+transpose)
  conv1_kernel<<<dim3(2,2048),512,0,stream>>>(x, w1p, c1b, y12);
  bn_stats_kernel<<<dim3(64,32),256,0,stream>>>(y12, stat, 64, 512);
  bn_finalize_kernel<<<1,128,0,stream>>>(stat, bn1g, bn1b, 64, 1.0f/(2048.0f*512.0f));
  poolT_kernel<64,256><<<2048,256,0,stream>>>(y12, stat, pool1t);

  // conv2 -> BN -> relu -> pool (+transpose)
  hipMemsetAsync(stat, 0, 256*sizeof(float), stream);
  conv2_kernel<<<2048,512,0,stream>>>(pool1t, w2p, c2b, y12);
  bn_stats_kernel<<<dim3(128,32),256,0,stream>>>(y12, stat, 128, 256);
  bn_finalize_kernel<<<1,128,0,stream>>>(stat, bn2g, bn2b, 128, 1.0f/(2048.0f*256.0f));
  poolT_kernel<128,128><<<2048,256,0,stream>>>(y12, stat, pool2t);

  // fused biLSTM (single dispatch, 16 waves/block)
  lstm_fused_kernel<<<256,1024,0,stream>>>(pool2t, wih_g, whh_g, bias_g, hsm);
  feats_kernel<<<2048,256,0,stream>>>(hsm, feats);

  // GAT x2
  node_gemm_kernel<256><<<64,256,0,stream>>>(feats, g1W, Wh1, whT);
  gat_s_kernel<<<512,256,0,stream>>>(Wh1, g1a, s1a, s2a);
  gat_attn16_kernel<<<128,512,0,stream>>>(whT, s1a, s2a, adj, h1, 1);
  node_gemm_kernel<128><<<64,256,0,stream>>>(h1, g2W, Wh2, whT);
  gat_s_kernel<<<512,256,0,stream>>>(Wh2, g2a, s1b, s2b);
  gat_attn16_kernel<<<128,512,0,stream>>>(whT, s1b, s2b, adj, outp, 0);
}